// Round 1
// baseline (452.054 us; speedup 1.0000x reference)
//
#include <hip/hip_runtime.h>
#include <hip/hip_bf16.h>

#define N_NODES 4096
#define BATCH   32
#define CIN     32
#define COUT    64
#define DEMB    16
#define NCOL    (BATCH * CIN)      // 1024 columns of the propagation GEMMs
#define KIO     (3 * CIN * COUT)   // 6144 generated-weight elements per node

typedef __bf16 bf16x8 __attribute__((ext_vector_type(8)));
typedef float  floatx4 __attribute__((ext_vector_type(4)));

__device__ inline void load_lds16(const void* g, void* l) {
    __builtin_amdgcn_global_load_lds(
        (const __attribute__((address_space(1))) void*)g,
        (__attribute__((address_space(3))) void*)l, 16, 0, 0);
}

// ---------------------------------------------------------------------------
// K0: A[n][m] = softmax_m(relu(E[n] . E[m]))  -> bf16, one block per row n
// ---------------------------------------------------------------------------
__global__ __launch_bounds__(256) void compute_A_kernel(
        const float* __restrict__ E, __hip_bfloat16* __restrict__ A) {
    const int n = blockIdx.x;
    const int t = threadIdx.x;
    __shared__ float En[DEMB];
    __shared__ float red[8];
    if (t < DEMB) En[t] = E[(size_t)n * DEMB + t];
    __syncthreads();
    const float4 e0 = *(const float4*)&En[0];
    const float4 e1 = *(const float4*)&En[4];
    const float4 e2 = *(const float4*)&En[8];
    const float4 e3 = *(const float4*)&En[12];

    float v[16];
    float mx = 0.0f;   // relu output >= 0, so 0 is a valid max seed
#pragma unroll
    for (int i = 0; i < 16; ++i) {
        const int m = t + i * 256;
        const float4* Em = (const float4*)&E[(size_t)m * DEMB];
        const float4 a0 = Em[0], a1 = Em[1], a2 = Em[2], a3 = Em[3];
        float d = e0.x*a0.x + e0.y*a0.y + e0.z*a0.z + e0.w*a0.w
                + e1.x*a1.x + e1.y*a1.y + e1.z*a1.z + e1.w*a1.w
                + e2.x*a2.x + e2.y*a2.y + e2.z*a2.z + e2.w*a2.w
                + e3.x*a3.x + e3.y*a3.y + e3.z*a3.z + e3.w*a3.w;
        d = fmaxf(d, 0.0f);
        v[i] = d;
        mx = fmaxf(mx, d);
    }
    const int wave = t >> 6, lane = t & 63;
#pragma unroll
    for (int off = 32; off > 0; off >>= 1) mx = fmaxf(mx, __shfl_xor(mx, off));
    if (lane == 0) red[wave] = mx;
    __syncthreads();
    mx = fmaxf(fmaxf(red[0], red[1]), fmaxf(red[2], red[3]));

    float s = 0.0f;
#pragma unroll
    for (int i = 0; i < 16; ++i) { v[i] = __expf(v[i] - mx); s += v[i]; }
#pragma unroll
    for (int off = 32; off > 0; off >>= 1) s += __shfl_xor(s, off);
    if (lane == 0) red[4 + wave] = s;
    __syncthreads();
    s = red[4] + red[5] + red[6] + red[7];
    const float inv = 1.0f / s;
#pragma unroll
    for (int i = 0; i < 16; ++i)
        A[(size_t)n * N_NODES + t + i * 256] = __float2bfloat16(v[i] * inv);
}

// ---------------------------------------------------------------------------
// K1: x[b][m][c] (fp32) -> Xt[m][b*32+c] (bf16) and Bt1[b*32+c][m] (bf16)
// one block per (64-row m-tile, batch b)
// ---------------------------------------------------------------------------
__global__ __launch_bounds__(256) void transpose_kernel(
        const float* __restrict__ x,
        __hip_bfloat16* __restrict__ Xt, __hip_bfloat16* __restrict__ Bt) {
    const int m0 = blockIdx.x * 64;
    const int b  = blockIdx.y;
    const int t  = threadIdx.x;
    __shared__ float tile[64][33];
    {
        const int ml = t >> 2, cg = (t & 3) * 8;
        const float* src = &x[((size_t)b * N_NODES + (m0 + ml)) * CIN + cg];
        const float4 r0 = *(const float4*)src;
        const float4 r1 = *(const float4*)(src + 4);
        tile[ml][cg+0] = r0.x; tile[ml][cg+1] = r0.y; tile[ml][cg+2] = r0.z; tile[ml][cg+3] = r0.w;
        tile[ml][cg+4] = r1.x; tile[ml][cg+5] = r1.y; tile[ml][cg+6] = r1.z; tile[ml][cg+7] = r1.w;
    }
    __syncthreads();
    {
        const int ml = t >> 2, cg = (t & 3) * 8;
        __hip_bfloat16* dst = &Xt[(size_t)(m0 + ml) * NCOL + b * CIN + cg];
#pragma unroll
        for (int j = 0; j < 8; ++j) dst[j] = __float2bfloat16(tile[ml][cg + j]);
    }
    {
        const int c = t >> 3, mg = (t & 7) * 8;
        __hip_bfloat16* dst = &Bt[(size_t)(b * CIN + c) * N_NODES + m0 + mg];
#pragma unroll
        for (int j = 0; j < 8; ++j) dst[j] = __float2bfloat16(tile[mg + j][c]);
    }
}

// ---------------------------------------------------------------------------
// K2: Wn[n][j] = sum_d E[n][d] * Wpool[d][j]   (j < 6144), bf16 out
// ---------------------------------------------------------------------------
__global__ __launch_bounds__(256) void gen_w_kernel(
        const float* __restrict__ E, const float* __restrict__ Wp,
        __hip_bfloat16* __restrict__ Wn) {
    const int jc = blockIdx.x * 256;
    const int nc = blockIdx.y * 64;
    const int t  = threadIdx.x;
    __shared__ float wp[DEMB][256];
    __shared__ float et[64][DEMB];
#pragma unroll
    for (int d = 0; d < DEMB; ++d) wp[d][t] = Wp[(size_t)d * KIO + jc + t];
    ((float4*)et)[t] = ((const float4*)&E[(size_t)nc * DEMB])[t];
    __syncthreads();
    float w[DEMB];
#pragma unroll
    for (int d = 0; d < DEMB; ++d) w[d] = wp[d][t];
    for (int nl = 0; nl < 64; ++nl) {
        float acc = 0.0f;
#pragma unroll
        for (int d = 0; d < DEMB; ++d) acc += et[nl][d] * w[d];
        Wn[(size_t)(nc + nl) * KIO + jc + t] = __float2bfloat16(acc);
    }
}

// ---------------------------------------------------------------------------
// K3: C[row][col] = sum_k A[row][k] * Bt[col][k]   (bf16 in, fp32 acc)
// 128x128 tile, BK=32, 4 waves, 4x4 grid of 16x16x32 MFMA per wave.
// Optional transposed second output Ct[col][row]; optional epilogue
// v = 2*acc - sub[row][col]  (Chebyshev T2 combine).
// ---------------------------------------------------------------------------
__global__ __launch_bounds__(256) void gemm_kernel(
        const __hip_bfloat16* __restrict__ A,    // [M][K]
        const __hip_bfloat16* __restrict__ Bt,   // [NC][K]
        __hip_bfloat16* __restrict__ Crow,       // [M][NC]
        __hip_bfloat16* __restrict__ Ct,         // [NC][M] or nullptr
        const __hip_bfloat16* __restrict__ sub,  // [M][NC] or nullptr
        int M, int NC, int K) {
    const int t    = threadIdx.x;
    const int row0 = blockIdx.y * 128;
    const int col0 = blockIdx.x * 128;
    __shared__ alignas(16) __hip_bfloat16 As[128 * 32];
    __shared__ alignas(16) __hip_bfloat16 Bs[128 * 32];
    const int lane = t & 63, wave = t >> 6;
    const int l16 = lane & 15, quad = lane >> 4;
    const int wrow = (wave >> 1) * 64, wcol = (wave & 1) * 64;

    floatx4 acc[4][4] = {};

    for (int kb = 0; kb < K; kb += 32) {
        __syncthreads();
#pragma unroll
        for (int it = 0; it < 2; ++it) {
            const int e = it * 2048 + t * 8;        // element index in 128x32 tile
            const int r = e >> 5, ko = e & 31;      // tile row, k offset
            load_lds16(&A [(size_t)(row0 + r) * K + kb + ko], &As[e]);
            load_lds16(&Bt[(size_t)(col0 + r) * K + kb + ko], &Bs[e]);
        }
        __syncthreads();
        bf16x8 af[4], bfr[4];
#pragma unroll
        for (int i = 0; i < 4; ++i)
            af[i]  = *(const bf16x8*)&As[(wrow + i * 16 + l16) * 32 + quad * 8];
#pragma unroll
        for (int i = 0; i < 4; ++i)
            bfr[i] = *(const bf16x8*)&Bs[(wcol + i * 16 + l16) * 32 + quad * 8];
#pragma unroll
        for (int i = 0; i < 4; ++i)
#pragma unroll
            for (int j = 0; j < 4; ++j)
                acc[i][j] = __builtin_amdgcn_mfma_f32_16x16x32_bf16(
                                af[i], bfr[j], acc[i][j], 0, 0, 0);
    }

#pragma unroll
    for (int i = 0; i < 4; ++i) {
#pragma unroll
        for (int j = 0; j < 4; ++j) {
#pragma unroll
            for (int r = 0; r < 4; ++r) {
                const int rg = row0 + wrow + i * 16 + quad * 4 + r;
                const int cg = col0 + wcol + j * 16 + l16;
                float v = acc[i][j][r];
                if (sub) v = 2.0f * v - __bfloat162float(sub[(size_t)rg * NC + cg]);
                const __hip_bfloat16 h = __float2bfloat16(v);
                Crow[(size_t)rg * NC + cg] = h;
                if (Ct) Ct[(size_t)cg * M + rg] = h;
            }
        }
    }
}

// ---------------------------------------------------------------------------
// K4: out[b][n][o] = sum_{k,i} xg_k[n][b*32+i] * Wn[n][k*2048+i*64+o] + bias
// one block per node n
// ---------------------------------------------------------------------------
__global__ __launch_bounds__(256) void final_kernel(
        const __hip_bfloat16* __restrict__ Xt, const __hip_bfloat16* __restrict__ Y1,
        const __hip_bfloat16* __restrict__ Y2, const __hip_bfloat16* __restrict__ Wn,
        const float* __restrict__ E, const float* __restrict__ bias_pool,
        float* __restrict__ out) {
    const int n = blockIdx.x;
    const int t = threadIdx.x;
    __shared__ float Ws[96][64];      // [k*32+i][o]
    __shared__ float g[3][32][33];    // [k][b][i] (+1 pad: kills 8-way bank conflict)
    __shared__ float bias[64];
#pragma unroll
    for (int j = 0; j < 24; ++j) {
        const int idx = t + j * 256;
        ((float*)Ws)[idx] = __bfloat162float(Wn[(size_t)n * KIO + idx]);
    }
    const __hip_bfloat16* srcs[3] = {Xt, Y1, Y2};
#pragma unroll
    for (int k = 0; k < 3; ++k)
#pragma unroll
        for (int j = 0; j < 4; ++j) {
            const int col = t + j * 256;
            g[k][col >> 5][col & 31] = __bfloat162float(srcs[k][(size_t)n * NCOL + col]);
        }
    if (t < 64) {
        float acc = 0.0f;
#pragma unroll
        for (int d = 0; d < DEMB; ++d) acc += E[(size_t)n * DEMB + d] * bias_pool[d * COUT + t];
        bias[t] = acc;
    }
    __syncthreads();

    const int b = t >> 3, og = (t & 7) * 8;
    float acc[8];
#pragma unroll
    for (int r = 0; r < 8; ++r) acc[r] = bias[og + r];
    for (int ki = 0; ki < 96; ++ki) {
        const float gv = g[ki >> 5][b][ki & 31];
        const float* wr = &Ws[ki][og];
        const float4 w0 = *(const float4*)wr;
        const float4 w1 = *(const float4*)(wr + 4);
        acc[0] += gv * w0.x; acc[1] += gv * w0.y; acc[2] += gv * w0.z; acc[3] += gv * w0.w;
        acc[4] += gv * w1.x; acc[5] += gv * w1.y; acc[6] += gv * w1.z; acc[7] += gv * w1.w;
    }
    float* o = &out[((size_t)b * N_NODES + n) * COUT + og];
    *(float4*)o       = make_float4(acc[0], acc[1], acc[2], acc[3]);
    *(float4*)(o + 4) = make_float4(acc[4], acc[5], acc[6], acc[7]);
}

// ---------------------------------------------------------------------------
extern "C" void kernel_launch(void* const* d_in, const int* in_sizes, int n_in,
                              void* d_out, int out_size, void* d_ws, size_t ws_size,
                              hipStream_t stream) {
    (void)in_sizes; (void)n_in; (void)out_size; (void)ws_size;
    const float* x  = (const float*)d_in[0];
    const float* E  = (const float*)d_in[1];
    // d_in[2] = laplacian_mx, unused by the reference forward
    const float* Wp = (const float*)d_in[3];
    const float* bp = (const float*)d_in[4];
    float* out = (float*)d_out;

    char* ws = (char*)d_ws;
    __hip_bfloat16* A   = (__hip_bfloat16*)(ws);                 // 33554432 B
    __hip_bfloat16* Xt  = (__hip_bfloat16*)(ws + 33554432);      //  8388608 B
    __hip_bfloat16* Bt1 = (__hip_bfloat16*)(ws + 41943040);      //  8388608 B (reused as Y2)
    __hip_bfloat16* Y1  = (__hip_bfloat16*)(ws + 50331648);      //  8388608 B
    __hip_bfloat16* Y1t = (__hip_bfloat16*)(ws + 58720256);      //  8388608 B
    __hip_bfloat16* Wn  = (__hip_bfloat16*)(ws + 67108864);      // 50331648 B -> 117440512 total

    compute_A_kernel<<<N_NODES, 256, 0, stream>>>(E, A);
    transpose_kernel<<<dim3(N_NODES / 64, BATCH), 256, 0, stream>>>(x, Xt, Bt1);
    gen_w_kernel<<<dim3(KIO / 256, N_NODES / 64), 256, 0, stream>>>(E, Wp, Wn);
    // Y1 = A @ X      (also emit Y1t for GEMM2's B-side)
    gemm_kernel<<<dim3(NCOL / 128, N_NODES / 128), 256, 0, stream>>>(
        A, Bt1, Y1, Y1t, nullptr, N_NODES, NCOL, N_NODES);
    // Y2 = 2*A@Y1 - X  (T2 combine fused in epilogue; dest reuses Bt1 space)
    gemm_kernel<<<dim3(NCOL / 128, N_NODES / 128), 256, 0, stream>>>(
        A, Y1t, Bt1, nullptr, Xt, N_NODES, NCOL, N_NODES);
    final_kernel<<<N_NODES, 256, 0, stream>>>(Xt, Y1, Bt1, Wn, E, bp, out);
}

// Round 2
// 391.960 us; speedup vs baseline: 1.1533x; 1.1533x over previous
//
#include <hip/hip_runtime.h>
#include <hip/hip_bf16.h>

#define N_NODES 4096
#define BATCH   32
#define CIN     32
#define COUT    64
#define DEMB    16
#define NCOL    (BATCH * CIN)      // 1024 columns of the propagation GEMMs
#define KIO     (3 * CIN * COUT)   // 6144 generated-weight elements per node

typedef __bf16 bf16x8 __attribute__((ext_vector_type(8)));
typedef float  floatx4 __attribute__((ext_vector_type(4)));

__device__ inline void load_lds16(const void* g, void* l) {
    __builtin_amdgcn_global_load_lds(
        (const __attribute__((address_space(1))) void*)g,
        (__attribute__((address_space(3))) void*)l, 16, 0, 0);
}

// ---------------------------------------------------------------------------
// K0: A[n][m] = softmax_m(relu(E[n] . E[m]))  -> bf16, one block per row n
// ---------------------------------------------------------------------------
__global__ __launch_bounds__(256) void compute_A_kernel(
        const float* __restrict__ E, __hip_bfloat16* __restrict__ A) {
    const int n = blockIdx.x;
    const int t = threadIdx.x;
    __shared__ float En[DEMB];
    __shared__ float red[8];
    if (t < DEMB) En[t] = E[(size_t)n * DEMB + t];
    __syncthreads();
    const float4 e0 = *(const float4*)&En[0];
    const float4 e1 = *(const float4*)&En[4];
    const float4 e2 = *(const float4*)&En[8];
    const float4 e3 = *(const float4*)&En[12];

    float v[16];
    float mx = 0.0f;   // relu output >= 0, so 0 is a valid max seed
#pragma unroll
    for (int i = 0; i < 16; ++i) {
        const int m = t + i * 256;
        const float4* Em = (const float4*)&E[(size_t)m * DEMB];
        const float4 a0 = Em[0], a1 = Em[1], a2 = Em[2], a3 = Em[3];
        float d = e0.x*a0.x + e0.y*a0.y + e0.z*a0.z + e0.w*a0.w
                + e1.x*a1.x + e1.y*a1.y + e1.z*a1.z + e1.w*a1.w
                + e2.x*a2.x + e2.y*a2.y + e2.z*a2.z + e2.w*a2.w
                + e3.x*a3.x + e3.y*a3.y + e3.z*a3.z + e3.w*a3.w;
        d = fmaxf(d, 0.0f);
        v[i] = d;
        mx = fmaxf(mx, d);
    }
    const int wave = t >> 6, lane = t & 63;
#pragma unroll
    for (int off = 32; off > 0; off >>= 1) mx = fmaxf(mx, __shfl_xor(mx, off));
    if (lane == 0) red[wave] = mx;
    __syncthreads();
    mx = fmaxf(fmaxf(red[0], red[1]), fmaxf(red[2], red[3]));

    float s = 0.0f;
#pragma unroll
    for (int i = 0; i < 16; ++i) { v[i] = __expf(v[i] - mx); s += v[i]; }
#pragma unroll
    for (int off = 32; off > 0; off >>= 1) s += __shfl_xor(s, off);
    if (lane == 0) red[4 + wave] = s;
    __syncthreads();
    s = red[4] + red[5] + red[6] + red[7];
    const float inv = 1.0f / s;
#pragma unroll
    for (int i = 0; i < 16; ++i)
        A[(size_t)n * N_NODES + t + i * 256] = __float2bfloat16(v[i] * inv);
}

// ---------------------------------------------------------------------------
// K1: x[b][m][c] (fp32) -> Xt[m][b*32+c] (bf16) and Bt1[b*32+c][m] (bf16)
// one block per (64-row m-tile, batch b)
// ---------------------------------------------------------------------------
__global__ __launch_bounds__(256) void transpose_kernel(
        const float* __restrict__ x,
        __hip_bfloat16* __restrict__ Xt, __hip_bfloat16* __restrict__ Bt) {
    const int m0 = blockIdx.x * 64;
    const int b  = blockIdx.y;
    const int t  = threadIdx.x;
    __shared__ float tile[64][33];
    {
        const int ml = t >> 2, cg = (t & 3) * 8;
        const float* src = &x[((size_t)b * N_NODES + (m0 + ml)) * CIN + cg];
        const float4 r0 = *(const float4*)src;
        const float4 r1 = *(const float4*)(src + 4);
        tile[ml][cg+0] = r0.x; tile[ml][cg+1] = r0.y; tile[ml][cg+2] = r0.z; tile[ml][cg+3] = r0.w;
        tile[ml][cg+4] = r1.x; tile[ml][cg+5] = r1.y; tile[ml][cg+6] = r1.z; tile[ml][cg+7] = r1.w;
    }
    __syncthreads();
    {
        const int ml = t >> 2, cg = (t & 3) * 8;
        __hip_bfloat16* dst = &Xt[(size_t)(m0 + ml) * NCOL + b * CIN + cg];
#pragma unroll
        for (int j = 0; j < 8; ++j) dst[j] = __float2bfloat16(tile[ml][cg + j]);
    }
    {
        const int c = t >> 3, mg = (t & 7) * 8;
        __hip_bfloat16* dst = &Bt[(size_t)(b * CIN + c) * N_NODES + m0 + mg];
#pragma unroll
        for (int j = 0; j < 8; ++j) dst[j] = __float2bfloat16(tile[mg + j][c]);
    }
}

// ---------------------------------------------------------------------------
// K2: Wn[n][j] = sum_d E[n][d] * Wpool[d][j]   (j < 6144), bf16 out
// ---------------------------------------------------------------------------
__global__ __launch_bounds__(256) void gen_w_kernel(
        const float* __restrict__ E, const float* __restrict__ Wp,
        __hip_bfloat16* __restrict__ Wn) {
    const int jc = blockIdx.x * 256;
    const int nc = blockIdx.y * 64;
    const int t  = threadIdx.x;
    __shared__ float wp[DEMB][256];
    __shared__ float et[64][DEMB];
#pragma unroll
    for (int d = 0; d < DEMB; ++d) wp[d][t] = Wp[(size_t)d * KIO + jc + t];
    ((float4*)et)[t] = ((const float4*)&E[(size_t)nc * DEMB])[t];
    __syncthreads();
    float w[DEMB];
#pragma unroll
    for (int d = 0; d < DEMB; ++d) w[d] = wp[d][t];
    for (int nl = 0; nl < 64; ++nl) {
        float acc = 0.0f;
#pragma unroll
        for (int d = 0; d < DEMB; ++d) acc += et[nl][d] * w[d];
        Wn[(size_t)(nc + nl) * KIO + jc + t] = __float2bfloat16(acc);
    }
}

// ---------------------------------------------------------------------------
// K3: split-K GEMM. P[z][row][col] = sum_{k in slice z} A[row][k]*Bt[col][k]
// 128x128 tile, BK=32, 4 waves, 4x4 grid of 16x16x32 MFMA per wave.
// grid (NC/128, M/128, 3) = 768 blocks -> ~3 blocks/CU resident so the
// barrier/vmcnt drain of one block overlaps another block's MFMA (m114).
// ---------------------------------------------------------------------------
__global__ __launch_bounds__(256) void gemm_splitk_kernel(
        const __hip_bfloat16* __restrict__ A,    // [M][K]
        const __hip_bfloat16* __restrict__ Bt,   // [NC][K]
        float* __restrict__ P,                   // [3][M][NC] fp32 partials
        int M, int NC, int K) {
    const int t    = threadIdx.x;
    const int col0 = blockIdx.x * 128;
    const int row0 = blockIdx.y * 128;
    const int z    = blockIdx.z;
    // k-iteration range for this z-slice
    const int iters = K >> 5;                  // 128 for K=4096
    const int q = iters / 3, rem = iters % 3;
    const int it0 = z * q + (z < rem ? z : rem);
    const int it1 = it0 + q + (z < rem ? 1 : 0);

    __shared__ alignas(16) __hip_bfloat16 As[128 * 32];
    __shared__ alignas(16) __hip_bfloat16 Bs[128 * 32];
    const int lane = t & 63, wave = t >> 6;
    const int l16 = lane & 15, quad = lane >> 4;
    const int wrow = (wave >> 1) * 64, wcol = (wave & 1) * 64;

    floatx4 acc[4][4] = {};

    for (int it = it0; it < it1; ++it) {
        const int kb = it << 5;
        __syncthreads();
#pragma unroll
        for (int s = 0; s < 2; ++s) {
            const int e = s * 2048 + t * 8;        // element index in 128x32 tile
            const int r = e >> 5, ko = e & 31;     // tile row, k offset
            load_lds16(&A [(size_t)(row0 + r) * K + kb + ko], &As[e]);
            load_lds16(&Bt[(size_t)(col0 + r) * K + kb + ko], &Bs[e]);
        }
        __syncthreads();
        bf16x8 af[4], bfr[4];
#pragma unroll
        for (int i = 0; i < 4; ++i)
            af[i]  = *(const bf16x8*)&As[(wrow + i * 16 + l16) * 32 + quad * 8];
#pragma unroll
        for (int i = 0; i < 4; ++i)
            bfr[i] = *(const bf16x8*)&Bs[(wcol + i * 16 + l16) * 32 + quad * 8];
#pragma unroll
        for (int i = 0; i < 4; ++i)
#pragma unroll
            for (int j = 0; j < 4; ++j)
                acc[i][j] = __builtin_amdgcn_mfma_f32_16x16x32_bf16(
                                af[i], bfr[j], acc[i][j], 0, 0, 0);
    }

    float* Pz = P + (size_t)z * M * NC;
#pragma unroll
    for (int i = 0; i < 4; ++i)
#pragma unroll
        for (int j = 0; j < 4; ++j)
#pragma unroll
            for (int r = 0; r < 4; ++r) {
                const int rg = row0 + wrow + i * 16 + quad * 4 + r;
                const int cg = col0 + wcol + j * 16 + l16;
                Pz[(size_t)rg * NC + cg] = acc[i][j][r];
            }
}

// ---------------------------------------------------------------------------
// K3b: combine1 -> Y1 = bf16(P0+P1+P2), plus transposed copy Y1t[col][row]
// 64x64 tile per block, LDS transpose with +1 padding.
// ---------------------------------------------------------------------------
__global__ __launch_bounds__(256) void combine1_kernel(
        const float* __restrict__ P, __hip_bfloat16* __restrict__ Y,
        __hip_bfloat16* __restrict__ Yt, int M, int NC) {
    const int c0 = blockIdx.x * 64, m0 = blockIdx.y * 64;
    const int t = threadIdx.x;
    __shared__ float tile[64][65];
    const size_t stride = (size_t)M * NC;
#pragma unroll
    for (int j = 0; j < 16; ++j) {
        const int lin = t + j * 256;
        const int r = lin >> 6, c = lin & 63;
        const size_t idx = (size_t)(m0 + r) * NC + c0 + c;
        const float s = P[idx] + P[idx + stride] + P[idx + 2 * stride];
        tile[r][c] = s;
        Y[idx] = __float2bfloat16(s);
    }
    __syncthreads();
#pragma unroll
    for (int j = 0; j < 16; ++j) {
        const int lin = t + j * 256;
        const int c = lin >> 6, r = lin & 63;
        Yt[(size_t)(c0 + c) * M + m0 + r] = __float2bfloat16(tile[r][c]);
    }
}

// ---------------------------------------------------------------------------
// K3c: combine2 -> Y2 = bf16(2*(P0+P1+P2) - Xt)   (Chebyshev T2), row-major
// ---------------------------------------------------------------------------
__global__ __launch_bounds__(256) void combine2_kernel(
        const float* __restrict__ P, const __hip_bfloat16* __restrict__ sub,
        __hip_bfloat16* __restrict__ Y2, int M, int NC) {
    const size_t stride = (size_t)M * NC;
    const size_t idx0 = (size_t)blockIdx.x * 4096 + threadIdx.x;
#pragma unroll
    for (int j = 0; j < 16; ++j) {
        const size_t idx = idx0 + (size_t)j * 256;
        const float s = P[idx] + P[idx + stride] + P[idx + 2 * stride];
        Y2[idx] = __float2bfloat16(2.0f * s - __bfloat162float(sub[idx]));
    }
}

// ---------------------------------------------------------------------------
// K4: out[b][n][o] = sum_{k,i} xg_k[n][b*32+i] * Wn[n][k*2048+i*64+o] + bias
// one block per node n
// ---------------------------------------------------------------------------
__global__ __launch_bounds__(256) void final_kernel(
        const __hip_bfloat16* __restrict__ Xt, const __hip_bfloat16* __restrict__ Y1,
        const __hip_bfloat16* __restrict__ Y2, const __hip_bfloat16* __restrict__ Wn,
        const float* __restrict__ E, const float* __restrict__ bias_pool,
        float* __restrict__ out) {
    const int n = blockIdx.x;
    const int t = threadIdx.x;
    __shared__ float Ws[96][64];      // [k*32+i][o]
    __shared__ float g[3][32][33];    // [k][b][i] (+1 pad: kills 8-way bank conflict)
    __shared__ float bias[64];
#pragma unroll
    for (int j = 0; j < 24; ++j) {
        const int idx = t + j * 256;
        ((float*)Ws)[idx] = __bfloat162float(Wn[(size_t)n * KIO + idx]);
    }
    const __hip_bfloat16* srcs[3] = {Xt, Y1, Y2};
#pragma unroll
    for (int k = 0; k < 3; ++k)
#pragma unroll
        for (int j = 0; j < 4; ++j) {
            const int col = t + j * 256;
            g[k][col >> 5][col & 31] = __bfloat162float(srcs[k][(size_t)n * NCOL + col]);
        }
    if (t < 64) {
        float acc = 0.0f;
#pragma unroll
        for (int d = 0; d < DEMB; ++d) acc += E[(size_t)n * DEMB + d] * bias_pool[d * COUT + t];
        bias[t] = acc;
    }
    __syncthreads();

    const int b = t >> 3, og = (t & 7) * 8;
    float acc[8];
#pragma unroll
    for (int r = 0; r < 8; ++r) acc[r] = bias[og + r];
    for (int ki = 0; ki < 96; ++ki) {
        const float gv = g[ki >> 5][b][ki & 31];
        const float* wr = &Ws[ki][og];
        const float4 w0 = *(const float4*)wr;
        const float4 w1 = *(const float4*)(wr + 4);
        acc[0] += gv * w0.x; acc[1] += gv * w0.y; acc[2] += gv * w0.z; acc[3] += gv * w0.w;
        acc[4] += gv * w1.x; acc[5] += gv * w1.y; acc[6] += gv * w1.z; acc[7] += gv * w1.w;
    }
    float* o = &out[((size_t)b * N_NODES + n) * COUT + og];
    *(float4*)o       = make_float4(acc[0], acc[1], acc[2], acc[3]);
    *(float4*)(o + 4) = make_float4(acc[4], acc[5], acc[6], acc[7]);
}

// ---------------------------------------------------------------------------
extern "C" void kernel_launch(void* const* d_in, const int* in_sizes, int n_in,
                              void* d_out, int out_size, void* d_ws, size_t ws_size,
                              hipStream_t stream) {
    (void)in_sizes; (void)n_in; (void)out_size; (void)ws_size;
    const float* x  = (const float*)d_in[0];
    const float* E  = (const float*)d_in[1];
    // d_in[2] = laplacian_mx, unused by the reference forward
    const float* Wp = (const float*)d_in[3];
    const float* bp = (const float*)d_in[4];
    float* out = (float*)d_out;

    char* ws = (char*)d_ws;
    __hip_bfloat16* A   = (__hip_bfloat16*)(ws);                 // 33554432 B
    __hip_bfloat16* Xt  = (__hip_bfloat16*)(ws + 33554432);      //  8388608 B
    __hip_bfloat16* Bt1 = (__hip_bfloat16*)(ws + 41943040);      //  8388608 B (X^T; reused as Y2)
    __hip_bfloat16* Y1  = (__hip_bfloat16*)(ws + 50331648);      //  8388608 B
    __hip_bfloat16* Y1t = (__hip_bfloat16*)(ws + 58720256);      //  8388608 B
    float*          P   = (float*)(ws + 67108864);               // 50331648 B fp32 partials [3][4096][1024]
    __hip_bfloat16* Wn  = (__hip_bfloat16*)(ws + 67108864);      // 50331648 B (SAME region: P dead before gen_w)
    // total ws use: 117440512 B (same as round 1)

    compute_A_kernel<<<N_NODES, 256, 0, stream>>>(E, A);
    transpose_kernel<<<dim3(N_NODES / 64, BATCH), 256, 0, stream>>>(x, Xt, Bt1);
    // Y1 = A @ X : split-K=3 -> 768 blocks (~3/CU)
    gemm_splitk_kernel<<<dim3(NCOL / 128, N_NODES / 128, 3), 256, 0, stream>>>(
        A, Bt1, P, N_NODES, NCOL, N_NODES);
    combine1_kernel<<<dim3(NCOL / 64, N_NODES / 64), 256, 0, stream>>>(
        P, Y1, Y1t, N_NODES, NCOL);
    // Y2 = 2*A@Y1 - X : same split-K, partials reused
    gemm_splitk_kernel<<<dim3(NCOL / 128, N_NODES / 128, 3), 256, 0, stream>>>(
        A, Y1t, P, N_NODES, NCOL, N_NODES);
    combine2_kernel<<<dim3(N_NODES * NCOL / 4096), 256, 0, stream>>>(
        P, Xt, Bt1, N_NODES, NCOL);
    // gen_w AFTER combine2: Wn shares the P region
    gen_w_kernel<<<dim3(KIO / 256, N_NODES / 64), 256, 0, stream>>>(E, Wp, Wn);
    final_kernel<<<N_NODES, 256, 0, stream>>>(Xt, Y1, Bt1, Wn, E, bp, out);
}

// Round 3
// 370.979 us; speedup vs baseline: 1.2185x; 1.0566x over previous
//
#include <hip/hip_runtime.h>
#include <hip/hip_bf16.h>

#define N_NODES 4096
#define BATCH   32
#define CIN     32
#define COUT    64
#define DEMB    16
#define NCOL    (BATCH * CIN)      // 1024 columns of the propagation GEMMs
#define KIO     (3 * CIN * COUT)   // 6144 generated-weight elements per node

typedef __bf16 bf16x8 __attribute__((ext_vector_type(8)));
typedef float  floatx4 __attribute__((ext_vector_type(4)));

__device__ inline void load_lds16(const void* g, void* l) {
    __builtin_amdgcn_global_load_lds(
        (const __attribute__((address_space(1))) void*)g,
        (__attribute__((address_space(3))) void*)l, 16, 0, 0);
}

// ---------------------------------------------------------------------------
// K0: A[n][m] = softmax_m(relu(E[n] . E[m]))  -> bf16.
// 256 blocks x 16 rows: wave w owns rows n0+4w..n0+4w+3 (En wave-uniform, in
// regs); E column-tiles staged to LDS transposed [d][col] (pad 260 -> lanes
// read consecutive cols, 2-way bank alias = free). relu>=0 and dot<=~30 so
// softmax without max-subtraction is exact in fp32 (shift invariance).
// Pass 1: per-row sum of exp (wave shfl reduce). Pass 2: recompute, scale,
// coalesced bf16 stores.
// ---------------------------------------------------------------------------
__global__ __launch_bounds__(256) void compute_A_kernel(
        const float* __restrict__ E, __hip_bfloat16* __restrict__ A) {
    const int n0   = blockIdx.x * 16;
    const int t    = threadIdx.x;
    const int lane = t & 63;
    const int rg   = t >> 6;            // wave id = row group
    __shared__ float Emt[DEMB][260];    // transposed E tile [d][col]

    float en[4][DEMB];                  // this wave's 4 rows of E (uniform)
#pragma unroll
    for (int r = 0; r < 4; ++r)
#pragma unroll
        for (int d = 0; d < DEMB; ++d)
            en[r][d] = E[(size_t)(n0 + rg * 4 + r) * DEMB + d];

    float sum[4] = {0.f, 0.f, 0.f, 0.f};

    // ---- pass 1: denominators ----
    for (int tile = 0; tile < 16; ++tile) {
        __syncthreads();
        {
            const float4* src = (const float4*)&E[(size_t)(tile * 256 + t) * DEMB];
            const float4 a0 = src[0], a1 = src[1], a2 = src[2], a3 = src[3];
            Emt[ 0][t] = a0.x; Emt[ 1][t] = a0.y; Emt[ 2][t] = a0.z; Emt[ 3][t] = a0.w;
            Emt[ 4][t] = a1.x; Emt[ 5][t] = a1.y; Emt[ 6][t] = a1.z; Emt[ 7][t] = a1.w;
            Emt[ 8][t] = a2.x; Emt[ 9][t] = a2.y; Emt[10][t] = a2.z; Emt[11][t] = a2.w;
            Emt[12][t] = a3.x; Emt[13][t] = a3.y; Emt[14][t] = a3.z; Emt[15][t] = a3.w;
        }
        __syncthreads();
#pragma unroll
        for (int j = 0; j < 4; ++j) {
            const int c = lane + j * 64;
            float em[DEMB];
#pragma unroll
            for (int d = 0; d < DEMB; ++d) em[d] = Emt[d][c];
#pragma unroll
            for (int r = 0; r < 4; ++r) {
                float dt = 0.f;
#pragma unroll
                for (int d = 0; d < DEMB; ++d) dt += en[r][d] * em[d];
                sum[r] += __expf(fmaxf(dt, 0.f));
            }
        }
    }
#pragma unroll
    for (int r = 0; r < 4; ++r) {
#pragma unroll
        for (int off = 32; off > 0; off >>= 1) sum[r] += __shfl_xor(sum[r], off);
    }
    const float inv0 = 1.0f / sum[0], inv1 = 1.0f / sum[1];
    const float inv2 = 1.0f / sum[2], inv3 = 1.0f / sum[3];
    const float inv[4] = {inv0, inv1, inv2, inv3};

    // ---- pass 2: normalize + store ----
    for (int tile = 0; tile < 16; ++tile) {
        __syncthreads();
        {
            const float4* src = (const float4*)&E[(size_t)(tile * 256 + t) * DEMB];
            const float4 a0 = src[0], a1 = src[1], a2 = src[2], a3 = src[3];
            Emt[ 0][t] = a0.x; Emt[ 1][t] = a0.y; Emt[ 2][t] = a0.z; Emt[ 3][t] = a0.w;
            Emt[ 4][t] = a1.x; Emt[ 5][t] = a1.y; Emt[ 6][t] = a1.z; Emt[ 7][t] = a1.w;
            Emt[ 8][t] = a2.x; Emt[ 9][t] = a2.y; Emt[10][t] = a2.z; Emt[11][t] = a2.w;
            Emt[12][t] = a3.x; Emt[13][t] = a3.y; Emt[14][t] = a3.z; Emt[15][t] = a3.w;
        }
        __syncthreads();
#pragma unroll
        for (int j = 0; j < 4; ++j) {
            const int c = lane + j * 64;
            float em[DEMB];
#pragma unroll
            for (int d = 0; d < DEMB; ++d) em[d] = Emt[d][c];
#pragma unroll
            for (int r = 0; r < 4; ++r) {
                float dt = 0.f;
#pragma unroll
                for (int d = 0; d < DEMB; ++d) dt += en[r][d] * em[d];
                const float v = __expf(fmaxf(dt, 0.f)) * inv[r];
                A[(size_t)(n0 + rg * 4 + r) * N_NODES + tile * 256 + c] =
                    __float2bfloat16(v);
            }
        }
    }
}

// ---------------------------------------------------------------------------
// K1: x[b][m][c] (fp32) -> Xt[m][b*32+c] (bf16) and Bt1[b*32+c][m] (bf16)
// one block per (64-row m-tile, batch b)
// ---------------------------------------------------------------------------
__global__ __launch_bounds__(256) void transpose_kernel(
        const float* __restrict__ x,
        __hip_bfloat16* __restrict__ Xt, __hip_bfloat16* __restrict__ Bt) {
    const int m0 = blockIdx.x * 64;
    const int b  = blockIdx.y;
    const int t  = threadIdx.x;
    __shared__ float tile[64][33];
    {
        const int ml = t >> 2, cg = (t & 3) * 8;
        const float* src = &x[((size_t)b * N_NODES + (m0 + ml)) * CIN + cg];
        const float4 r0 = *(const float4*)src;
        const float4 r1 = *(const float4*)(src + 4);
        tile[ml][cg+0] = r0.x; tile[ml][cg+1] = r0.y; tile[ml][cg+2] = r0.z; tile[ml][cg+3] = r0.w;
        tile[ml][cg+4] = r1.x; tile[ml][cg+5] = r1.y; tile[ml][cg+6] = r1.z; tile[ml][cg+7] = r1.w;
    }
    __syncthreads();
    {
        const int ml = t >> 2, cg = (t & 3) * 8;
        __hip_bfloat16* dst = &Xt[(size_t)(m0 + ml) * NCOL + b * CIN + cg];
#pragma unroll
        for (int j = 0; j < 8; ++j) dst[j] = __float2bfloat16(tile[ml][cg + j]);
    }
    {
        const int c = t >> 3, mg = (t & 7) * 8;
        __hip_bfloat16* dst = &Bt[(size_t)(b * CIN + c) * N_NODES + m0 + mg];
#pragma unroll
        for (int j = 0; j < 8; ++j) dst[j] = __float2bfloat16(tile[mg + j][c]);
    }
}

// ---------------------------------------------------------------------------
// K2: Wn[n][j] = sum_d E[n][d] * Wpool[d][j]   (j < 6144), bf16 out
// ---------------------------------------------------------------------------
__global__ __launch_bounds__(256) void gen_w_kernel(
        const float* __restrict__ E, const float* __restrict__ Wp,
        __hip_bfloat16* __restrict__ Wn) {
    const int jc = blockIdx.x * 256;
    const int nc = blockIdx.y * 64;
    const int t  = threadIdx.x;
    __shared__ float wp[DEMB][256];
    __shared__ float et[64][DEMB];
#pragma unroll
    for (int d = 0; d < DEMB; ++d) wp[d][t] = Wp[(size_t)d * KIO + jc + t];
    ((float4*)et)[t] = ((const float4*)&E[(size_t)nc * DEMB])[t];
    __syncthreads();
    float w[DEMB];
#pragma unroll
    for (int d = 0; d < DEMB; ++d) w[d] = wp[d][t];
    for (int nl = 0; nl < 64; ++nl) {
        float acc = 0.0f;
#pragma unroll
        for (int d = 0; d < DEMB; ++d) acc += et[nl][d] * w[d];
        Wn[(size_t)(nc + nl) * KIO + jc + t] = __float2bfloat16(acc);
    }
}

// ---------------------------------------------------------------------------
// K3: split-K GEMM. P[z][row][col] = sum_{k in slice z} A[row][k]*Bt[col][k]
// 128x128 tile, BK=32, 4 waves, 4x4 grid of 16x16x32 MFMA per wave.
// grid (NC/128, M/128, 3) = 768 blocks -> ~3 blocks/CU resident so the
// barrier/vmcnt drain of one block overlaps another block's MFMA (m114).
// ---------------------------------------------------------------------------
__global__ __launch_bounds__(256) void gemm_splitk_kernel(
        const __hip_bfloat16* __restrict__ A,    // [M][K]
        const __hip_bfloat16* __restrict__ Bt,   // [NC][K]
        float* __restrict__ P,                   // [3][M][NC] fp32 partials
        int M, int NC, int K) {
    const int t    = threadIdx.x;
    const int col0 = blockIdx.x * 128;
    const int row0 = blockIdx.y * 128;
    const int z    = blockIdx.z;
    // k-iteration range for this z-slice
    const int iters = K >> 5;                  // 128 for K=4096
    const int q = iters / 3, rem = iters % 3;
    const int it0 = z * q + (z < rem ? z : rem);
    const int it1 = it0 + q + (z < rem ? 1 : 0);

    __shared__ alignas(16) __hip_bfloat16 As[128 * 32];
    __shared__ alignas(16) __hip_bfloat16 Bs[128 * 32];
    const int lane = t & 63, wave = t >> 6;
    const int l16 = lane & 15, quad = lane >> 4;
    const int wrow = (wave >> 1) * 64, wcol = (wave & 1) * 64;

    floatx4 acc[4][4] = {};

    for (int it = it0; it < it1; ++it) {
        const int kb = it << 5;
        __syncthreads();
#pragma unroll
        for (int s = 0; s < 2; ++s) {
            const int e = s * 2048 + t * 8;        // element index in 128x32 tile
            const int r = e >> 5, ko = e & 31;     // tile row, k offset
            load_lds16(&A [(size_t)(row0 + r) * K + kb + ko], &As[e]);
            load_lds16(&Bt[(size_t)(col0 + r) * K + kb + ko], &Bs[e]);
        }
        __syncthreads();
        bf16x8 af[4], bfr[4];
#pragma unroll
        for (int i = 0; i < 4; ++i)
            af[i]  = *(const bf16x8*)&As[(wrow + i * 16 + l16) * 32 + quad * 8];
#pragma unroll
        for (int i = 0; i < 4; ++i)
            bfr[i] = *(const bf16x8*)&Bs[(wcol + i * 16 + l16) * 32 + quad * 8];
#pragma unroll
        for (int i = 0; i < 4; ++i)
#pragma unroll
            for (int j = 0; j < 4; ++j)
                acc[i][j] = __builtin_amdgcn_mfma_f32_16x16x32_bf16(
                                af[i], bfr[j], acc[i][j], 0, 0, 0);
    }

    float* Pz = P + (size_t)z * M * NC;
#pragma unroll
    for (int i = 0; i < 4; ++i)
#pragma unroll
        for (int j = 0; j < 4; ++j)
#pragma unroll
            for (int r = 0; r < 4; ++r) {
                const int rg = row0 + wrow + i * 16 + quad * 4 + r;
                const int cg = col0 + wcol + j * 16 + l16;
                Pz[(size_t)rg * NC + cg] = acc[i][j][r];
            }
}

// ---------------------------------------------------------------------------
// K3b: combine1 -> Y1 = bf16(P0+P1+P2), plus transposed copy Y1t[col][row]
// 64x64 tile per block, LDS transpose with +1 padding.
// ---------------------------------------------------------------------------
__global__ __launch_bounds__(256) void combine1_kernel(
        const float* __restrict__ P, __hip_bfloat16* __restrict__ Y,
        __hip_bfloat16* __restrict__ Yt, int M, int NC) {
    const int c0 = blockIdx.x * 64, m0 = blockIdx.y * 64;
    const int t = threadIdx.x;
    __shared__ float tile[64][65];
    const size_t stride = (size_t)M * NC;
#pragma unroll
    for (int j = 0; j < 16; ++j) {
        const int lin = t + j * 256;
        const int r = lin >> 6, c = lin & 63;
        const size_t idx = (size_t)(m0 + r) * NC + c0 + c;
        const float s = P[idx] + P[idx + stride] + P[idx + 2 * stride];
        tile[r][c] = s;
        Y[idx] = __float2bfloat16(s);
    }
    __syncthreads();
#pragma unroll
    for (int j = 0; j < 16; ++j) {
        const int lin = t + j * 256;
        const int c = lin >> 6, r = lin & 63;
        Yt[(size_t)(c0 + c) * M + m0 + r] = __float2bfloat16(tile[r][c]);
    }
}

// ---------------------------------------------------------------------------
// K3c: combine2 -> Y2 = bf16(2*(P0+P1+P2) - Xt)   (Chebyshev T2), row-major
// ---------------------------------------------------------------------------
__global__ __launch_bounds__(256) void combine2_kernel(
        const float* __restrict__ P, const __hip_bfloat16* __restrict__ sub,
        __hip_bfloat16* __restrict__ Y2, int M, int NC) {
    const size_t stride = (size_t)M * NC;
    const size_t idx0 = (size_t)blockIdx.x * 4096 + threadIdx.x;
#pragma unroll
    for (int j = 0; j < 16; ++j) {
        const size_t idx = idx0 + (size_t)j * 256;
        const float s = P[idx] + P[idx + stride] + P[idx + 2 * stride];
        Y2[idx] = __float2bfloat16(2.0f * s - __bfloat162float(sub[idx]));
    }
}

// ---------------------------------------------------------------------------
// K4: out[b][n][o] = sum_{k,i} xg_k[n][b*32+i] * Wn[n][k*2048+i*64+o] + bias
// one block per node n
// ---------------------------------------------------------------------------
__global__ __launch_bounds__(256) void final_kernel(
        const __hip_bfloat16* __restrict__ Xt, const __hip_bfloat16* __restrict__ Y1,
        const __hip_bfloat16* __restrict__ Y2, const __hip_bfloat16* __restrict__ Wn,
        const float* __restrict__ E, const float* __restrict__ bias_pool,
        float* __restrict__ out) {
    const int n = blockIdx.x;
    const int t = threadIdx.x;
    __shared__ float Ws[96][64];      // [k*32+i][o]
    __shared__ float g[3][32][33];    // [k][b][i] (+1 pad: kills 8-way bank conflict)
    __shared__ float bias[64];
#pragma unroll
    for (int j = 0; j < 24; ++j) {
        const int idx = t + j * 256;
        ((float*)Ws)[idx] = __bfloat162float(Wn[(size_t)n * KIO + idx]);
    }
    const __hip_bfloat16* srcs[3] = {Xt, Y1, Y2};
#pragma unroll
    for (int k = 0; k < 3; ++k)
#pragma unroll
        for (int j = 0; j < 4; ++j) {
            const int col = t + j * 256;
            g[k][col >> 5][col & 31] = __bfloat162float(srcs[k][(size_t)n * NCOL + col]);
        }
    if (t < 64) {
        float acc = 0.0f;
#pragma unroll
        for (int d = 0; d < DEMB; ++d) acc += E[(size_t)n * DEMB + d] * bias_pool[d * COUT + t];
        bias[t] = acc;
    }
    __syncthreads();

    const int b = t >> 3, og = (t & 7) * 8;
    float acc[8];
#pragma unroll
    for (int r = 0; r < 8; ++r) acc[r] = bias[og + r];
    for (int ki = 0; ki < 96; ++ki) {
        const float gv = g[ki >> 5][b][ki & 31];
        const float* wr = &Ws[ki][og];
        const float4 w0 = *(const float4*)wr;
        const float4 w1 = *(const float4*)(wr + 4);
        acc[0] += gv * w0.x; acc[1] += gv * w0.y; acc[2] += gv * w0.z; acc[3] += gv * w0.w;
        acc[4] += gv * w1.x; acc[5] += gv * w1.y; acc[6] += gv * w1.z; acc[7] += gv * w1.w;
    }
    float* o = &out[((size_t)b * N_NODES + n) * COUT + og];
    *(float4*)o       = make_float4(acc[0], acc[1], acc[2], acc[3]);
    *(float4*)(o + 4) = make_float4(acc[4], acc[5], acc[6], acc[7]);
}

// ---------------------------------------------------------------------------
extern "C" void kernel_launch(void* const* d_in, const int* in_sizes, int n_in,
                              void* d_out, int out_size, void* d_ws, size_t ws_size,
                              hipStream_t stream) {
    (void)in_sizes; (void)n_in; (void)out_size; (void)ws_size;
    const float* x  = (const float*)d_in[0];
    const float* E  = (const float*)d_in[1];
    // d_in[2] = laplacian_mx, unused by the reference forward
    const float* Wp = (const float*)d_in[3];
    const float* bp = (const float*)d_in[4];
    float* out = (float*)d_out;

    char* ws = (char*)d_ws;
    __hip_bfloat16* A   = (__hip_bfloat16*)(ws);                 // 33554432 B
    __hip_bfloat16* Xt  = (__hip_bfloat16*)(ws + 33554432);      //  8388608 B
    __hip_bfloat16* Bt1 = (__hip_bfloat16*)(ws + 41943040);      //  8388608 B (X^T; reused as Y2)
    __hip_bfloat16* Y1  = (__hip_bfloat16*)(ws + 50331648);      //  8388608 B
    __hip_bfloat16* Y1t = (__hip_bfloat16*)(ws + 58720256);      //  8388608 B
    float*          P   = (float*)(ws + 67108864);               // 50331648 B fp32 partials [3][4096][1024]
    __hip_bfloat16* Wn  = (__hip_bfloat16*)(ws + 67108864);      // 50331648 B (SAME region: P dead before gen_w)
    // total ws use: 117440512 B (same as round 1)

    compute_A_kernel<<<N_NODES / 16, 256, 0, stream>>>(E, A);
    transpose_kernel<<<dim3(N_NODES / 64, BATCH), 256, 0, stream>>>(x, Xt, Bt1);
    // Y1 = A @ X : split-K=3 -> 768 blocks (~3/CU)
    gemm_splitk_kernel<<<dim3(NCOL / 128, N_NODES / 128, 3), 256, 0, stream>>>(
        A, Bt1, P, N_NODES, NCOL, N_NODES);
    combine1_kernel<<<dim3(NCOL / 64, N_NODES / 64), 256, 0, stream>>>(
        P, Y1, Y1t, N_NODES, NCOL);
    // Y2 = 2*A@Y1 - X : same split-K, partials reused
    gemm_splitk_kernel<<<dim3(NCOL / 128, N_NODES / 128, 3), 256, 0, stream>>>(
        A, Y1t, P, N_NODES, NCOL, N_NODES);
    combine2_kernel<<<dim3(N_NODES * NCOL / 4096), 256, 0, stream>>>(
        P, Xt, Bt1, N_NODES, NCOL);
    // gen_w AFTER combine2: Wn shares the P region
    gen_w_kernel<<<dim3(KIO / 256, N_NODES / 64), 256, 0, stream>>>(E, Wp, Wn);
    final_kernel<<<N_NODES, 256, 0, stream>>>(Xt, Y1, Bt1, Wn, E, bp, out);
}

// Round 4
// 360.094 us; speedup vs baseline: 1.2554x; 1.0302x over previous
//
#include <hip/hip_runtime.h>
#include <hip/hip_bf16.h>

#define N_NODES 4096
#define BATCH   32
#define CIN     32
#define COUT    64
#define DEMB    16
#define NCOL    (BATCH * CIN)      // 1024 columns of the propagation GEMMs
#define KIO     (3 * CIN * COUT)   // 6144 generated-weight elements per node
#define SPLITK  4

typedef __bf16 bf16x8 __attribute__((ext_vector_type(8)));
typedef float  floatx4 __attribute__((ext_vector_type(4)));

__device__ inline void load_lds16(const void* g, void* l) {
    __builtin_amdgcn_global_load_lds(
        (const __attribute__((address_space(1))) void*)g,
        (__attribute__((address_space(3))) void*)l, 16, 0, 0);
}

// ---------------------------------------------------------------------------
// K0: A[n][m] = softmax_m(relu(E[n] . E[m]))  -> bf16.
// 256 blocks x 16 rows; E column-tiles staged to LDS transposed [d][col].
// relu>=0 and dot bounded, so softmax without max-subtraction is exact.
// ---------------------------------------------------------------------------
__global__ __launch_bounds__(256) void compute_A_kernel(
        const float* __restrict__ E, __hip_bfloat16* __restrict__ A) {
    const int n0   = blockIdx.x * 16;
    const int t    = threadIdx.x;
    const int lane = t & 63;
    const int rg   = t >> 6;            // wave id = row group
    __shared__ float Emt[DEMB][260];    // transposed E tile [d][col]

    float en[4][DEMB];                  // this wave's 4 rows of E (uniform)
#pragma unroll
    for (int r = 0; r < 4; ++r)
#pragma unroll
        for (int d = 0; d < DEMB; ++d)
            en[r][d] = E[(size_t)(n0 + rg * 4 + r) * DEMB + d];

    float sum[4] = {0.f, 0.f, 0.f, 0.f};

    // ---- pass 1: denominators ----
    for (int tile = 0; tile < 16; ++tile) {
        __syncthreads();
        {
            const float4* src = (const float4*)&E[(size_t)(tile * 256 + t) * DEMB];
            const float4 a0 = src[0], a1 = src[1], a2 = src[2], a3 = src[3];
            Emt[ 0][t] = a0.x; Emt[ 1][t] = a0.y; Emt[ 2][t] = a0.z; Emt[ 3][t] = a0.w;
            Emt[ 4][t] = a1.x; Emt[ 5][t] = a1.y; Emt[ 6][t] = a1.z; Emt[ 7][t] = a1.w;
            Emt[ 8][t] = a2.x; Emt[ 9][t] = a2.y; Emt[10][t] = a2.z; Emt[11][t] = a2.w;
            Emt[12][t] = a3.x; Emt[13][t] = a3.y; Emt[14][t] = a3.z; Emt[15][t] = a3.w;
        }
        __syncthreads();
#pragma unroll
        for (int j = 0; j < 4; ++j) {
            const int c = lane + j * 64;
            float em[DEMB];
#pragma unroll
            for (int d = 0; d < DEMB; ++d) em[d] = Emt[d][c];
#pragma unroll
            for (int r = 0; r < 4; ++r) {
                float dt = 0.f;
#pragma unroll
                for (int d = 0; d < DEMB; ++d) dt += en[r][d] * em[d];
                sum[r] += __expf(fmaxf(dt, 0.f));
            }
        }
    }
#pragma unroll
    for (int r = 0; r < 4; ++r) {
#pragma unroll
        for (int off = 32; off > 0; off >>= 1) sum[r] += __shfl_xor(sum[r], off);
    }
    const float inv[4] = {1.0f / sum[0], 1.0f / sum[1], 1.0f / sum[2], 1.0f / sum[3]};

    // ---- pass 2: normalize + store ----
    for (int tile = 0; tile < 16; ++tile) {
        __syncthreads();
        {
            const float4* src = (const float4*)&E[(size_t)(tile * 256 + t) * DEMB];
            const float4 a0 = src[0], a1 = src[1], a2 = src[2], a3 = src[3];
            Emt[ 0][t] = a0.x; Emt[ 1][t] = a0.y; Emt[ 2][t] = a0.z; Emt[ 3][t] = a0.w;
            Emt[ 4][t] = a1.x; Emt[ 5][t] = a1.y; Emt[ 6][t] = a1.z; Emt[ 7][t] = a1.w;
            Emt[ 8][t] = a2.x; Emt[ 9][t] = a2.y; Emt[10][t] = a2.z; Emt[11][t] = a2.w;
            Emt[12][t] = a3.x; Emt[13][t] = a3.y; Emt[14][t] = a3.z; Emt[15][t] = a3.w;
        }
        __syncthreads();
#pragma unroll
        for (int j = 0; j < 4; ++j) {
            const int c = lane + j * 64;
            float em[DEMB];
#pragma unroll
            for (int d = 0; d < DEMB; ++d) em[d] = Emt[d][c];
#pragma unroll
            for (int r = 0; r < 4; ++r) {
                float dt = 0.f;
#pragma unroll
                for (int d = 0; d < DEMB; ++d) dt += en[r][d] * em[d];
                const float v = __expf(fmaxf(dt, 0.f)) * inv[r];
                A[(size_t)(n0 + rg * 4 + r) * N_NODES + tile * 256 + c] =
                    __float2bfloat16(v);
            }
        }
    }
}

// ---------------------------------------------------------------------------
// K1: x[b][m][c] (fp32) -> Xt[m][b*32+c] (bf16) and Bt1[b*32+c][m] (bf16)
// ---------------------------------------------------------------------------
__global__ __launch_bounds__(256) void transpose_kernel(
        const float* __restrict__ x,
        __hip_bfloat16* __restrict__ Xt, __hip_bfloat16* __restrict__ Bt) {
    const int m0 = blockIdx.x * 64;
    const int b  = blockIdx.y;
    const int t  = threadIdx.x;
    __shared__ float tile[64][33];
    {
        const int ml = t >> 2, cg = (t & 3) * 8;
        const float* src = &x[((size_t)b * N_NODES + (m0 + ml)) * CIN + cg];
        const float4 r0 = *(const float4*)src;
        const float4 r1 = *(const float4*)(src + 4);
        tile[ml][cg+0] = r0.x; tile[ml][cg+1] = r0.y; tile[ml][cg+2] = r0.z; tile[ml][cg+3] = r0.w;
        tile[ml][cg+4] = r1.x; tile[ml][cg+5] = r1.y; tile[ml][cg+6] = r1.z; tile[ml][cg+7] = r1.w;
    }
    __syncthreads();
    {
        const int ml = t >> 2, cg = (t & 3) * 8;
        __hip_bfloat16* dst = &Xt[(size_t)(m0 + ml) * NCOL + b * CIN + cg];
#pragma unroll
        for (int j = 0; j < 8; ++j) dst[j] = __float2bfloat16(tile[ml][cg + j]);
    }
    {
        const int c = t >> 3, mg = (t & 7) * 8;
        __hip_bfloat16* dst = &Bt[(size_t)(b * CIN + c) * N_NODES + m0 + mg];
#pragma unroll
        for (int j = 0; j < 8; ++j) dst[j] = __float2bfloat16(tile[mg + j][c]);
    }
}

// ---------------------------------------------------------------------------
// K2: Wn[n][j] = sum_d E[n][d] * Wpool[d][j]   (j < 6144), bf16 out
// ---------------------------------------------------------------------------
__global__ __launch_bounds__(256) void gen_w_kernel(
        const float* __restrict__ E, const float* __restrict__ Wp,
        __hip_bfloat16* __restrict__ Wn) {
    const int jc = blockIdx.x * 256;
    const int nc = blockIdx.y * 64;
    const int t  = threadIdx.x;
    __shared__ float wp[DEMB][256];
    __shared__ float et[64][DEMB];
#pragma unroll
    for (int d = 0; d < DEMB; ++d) wp[d][t] = Wp[(size_t)d * KIO + jc + t];
    ((float4*)et)[t] = ((const float4*)&E[(size_t)nc * DEMB])[t];
    __syncthreads();
    float w[DEMB];
#pragma unroll
    for (int d = 0; d < DEMB; ++d) w[d] = wp[d][t];
    for (int nl = 0; nl < 64; ++nl) {
        float acc = 0.0f;
#pragma unroll
        for (int d = 0; d < DEMB; ++d) acc += et[nl][d] * w[d];
        Wn[(size_t)(nc + nl) * KIO + jc + t] = __float2bfloat16(acc);
    }
}

// ---------------------------------------------------------------------------
// K3: split-K GEMM. P[z][row][col] = sum_{k in slice z} A[row][k]*Bt[col][k]
// 128x128 tile, BK=32, SPLITK=4 -> 1024 blocks (4/CU, m97's config).
// Partials stored bf16 (halves P traffic; error << threshold headroom).
// ---------------------------------------------------------------------------
__global__ __launch_bounds__(256) void gemm_splitk_kernel(
        const __hip_bfloat16* __restrict__ A,    // [M][K]
        const __hip_bfloat16* __restrict__ Bt,   // [NC][K]
        __hip_bfloat16* __restrict__ P,          // [SPLITK][M][NC] bf16 partials
        int M, int NC, int K) {
    const int t    = threadIdx.x;
    const int col0 = blockIdx.x * 128;
    const int row0 = blockIdx.y * 128;
    const int z    = blockIdx.z;
    const int iters = K >> 5;
    const int q = iters / SPLITK, rem = iters % SPLITK;
    const int it0 = z * q + (z < rem ? z : rem);
    const int it1 = it0 + q + (z < rem ? 1 : 0);

    __shared__ alignas(16) __hip_bfloat16 As[128 * 32];
    __shared__ alignas(16) __hip_bfloat16 Bs[128 * 32];
    const int lane = t & 63, wave = t >> 6;
    const int l16 = lane & 15, quad = lane >> 4;
    const int wrow = (wave >> 1) * 64, wcol = (wave & 1) * 64;

    floatx4 acc[4][4] = {};

    for (int it = it0; it < it1; ++it) {
        const int kb = it << 5;
        __syncthreads();
#pragma unroll
        for (int s = 0; s < 2; ++s) {
            const int e = s * 2048 + t * 8;
            const int r = e >> 5, ko = e & 31;
            load_lds16(&A [(size_t)(row0 + r) * K + kb + ko], &As[e]);
            load_lds16(&Bt[(size_t)(col0 + r) * K + kb + ko], &Bs[e]);
        }
        __syncthreads();
        bf16x8 af[4], bfr[4];
#pragma unroll
        for (int i = 0; i < 4; ++i)
            af[i]  = *(const bf16x8*)&As[(wrow + i * 16 + l16) * 32 + quad * 8];
#pragma unroll
        for (int i = 0; i < 4; ++i)
            bfr[i] = *(const bf16x8*)&Bs[(wcol + i * 16 + l16) * 32 + quad * 8];
#pragma unroll
        for (int i = 0; i < 4; ++i)
#pragma unroll
            for (int j = 0; j < 4; ++j)
                acc[i][j] = __builtin_amdgcn_mfma_f32_16x16x32_bf16(
                                af[i], bfr[j], acc[i][j], 0, 0, 0);
    }

    __hip_bfloat16* Pz = P + (size_t)z * M * NC;
#pragma unroll
    for (int i = 0; i < 4; ++i)
#pragma unroll
        for (int j = 0; j < 4; ++j)
#pragma unroll
            for (int r = 0; r < 4; ++r) {
                const int rg = row0 + wrow + i * 16 + quad * 4 + r;
                const int cg = col0 + wcol + j * 16 + l16;
                Pz[(size_t)rg * NC + cg] = __float2bfloat16(acc[i][j][r]);
            }
}

// ---------------------------------------------------------------------------
// K3b: combine1 -> Y1 = bf16(sum_z Pz), plus transposed copy Y1t[col][row]
// ---------------------------------------------------------------------------
__global__ __launch_bounds__(256) void combine1_kernel(
        const __hip_bfloat16* __restrict__ P, __hip_bfloat16* __restrict__ Y,
        __hip_bfloat16* __restrict__ Yt, int M, int NC) {
    const int c0 = blockIdx.x * 64, m0 = blockIdx.y * 64;
    const int t = threadIdx.x;
    __shared__ float tile[64][65];
    const size_t stride = (size_t)M * NC;
#pragma unroll
    for (int j = 0; j < 16; ++j) {
        const int lin = t + j * 256;
        const int r = lin >> 6, c = lin & 63;
        const size_t idx = (size_t)(m0 + r) * NC + c0 + c;
        float s = 0.f;
#pragma unroll
        for (int z = 0; z < SPLITK; ++z) s += __bfloat162float(P[idx + z * stride]);
        tile[r][c] = s;
        Y[idx] = __float2bfloat16(s);
    }
    __syncthreads();
#pragma unroll
    for (int j = 0; j < 16; ++j) {
        const int lin = t + j * 256;
        const int c = lin >> 6, r = lin & 63;
        Yt[(size_t)(c0 + c) * M + m0 + r] = __float2bfloat16(tile[r][c]);
    }
}

// ---------------------------------------------------------------------------
// K3c: combine2 -> Y2 = bf16(2*sum_z Pz - Xt)   (Chebyshev T2), row-major
// ---------------------------------------------------------------------------
__global__ __launch_bounds__(256) void combine2_kernel(
        const __hip_bfloat16* __restrict__ P, const __hip_bfloat16* __restrict__ sub,
        __hip_bfloat16* __restrict__ Y2, int M, int NC) {
    const size_t stride = (size_t)M * NC;
    const size_t idx0 = (size_t)blockIdx.x * 4096 + threadIdx.x;
#pragma unroll
    for (int j = 0; j < 16; ++j) {
        const size_t idx = idx0 + (size_t)j * 256;
        float s = 0.f;
#pragma unroll
        for (int z = 0; z < SPLITK; ++z) s += __bfloat162float(P[idx + z * stride]);
        Y2[idx] = __float2bfloat16(2.0f * s - __bfloat162float(sub[idx]));
    }
}

// ---------------------------------------------------------------------------
// K4: per-node grouped GEMM via MFMA. out[b][n][o] = sum_k G[b][k] W[k][o] + bias
//   G[b][k=c*32+i]   = srcs[c][n*1024 + b*32 + i]   (A-frag: direct 16B loads)
//   W[k][o]          = Wn[n*6144 + k*64 + o]        (B-frag: 8 strided u16 loads)
// One wave per node, 4 nodes per block. C/D layout: row=quad*4+r, col=l16
// (same mapping as the verified main GEMM).
// ---------------------------------------------------------------------------
__global__ __launch_bounds__(256) void final_kernel(
        const __hip_bfloat16* __restrict__ Xt, const __hip_bfloat16* __restrict__ Y1,
        const __hip_bfloat16* __restrict__ Y2, const __hip_bfloat16* __restrict__ Wn,
        const float* __restrict__ E, const float* __restrict__ bias_pool,
        float* __restrict__ out) {
    const int t    = threadIdx.x;
    const int lane = t & 63, wave = t >> 6;
    const int l16  = lane & 15, quad = lane >> 4;
    const int n    = blockIdx.x * 4 + wave;

    const __hip_bfloat16* srcs[3] = {Xt, Y1, Y2};
    const __hip_bfloat16* Wnode = Wn + (size_t)n * KIO;

    floatx4 acc[2][4] = {};   // [mt][ot]

#pragma unroll
    for (int c = 0; c < 3; ++c) {
        bf16x8 af[2];
#pragma unroll
        for (int mt = 0; mt < 2; ++mt)
            af[mt] = *(const bf16x8*)&srcs[c][(size_t)n * NCOL +
                                              (mt * 16 + l16) * 32 + quad * 8];
#pragma unroll
        for (int ot = 0; ot < 4; ++ot) {
            bf16x8 bfr;
#pragma unroll
            for (int j = 0; j < 8; ++j)
                bfr[j] = (__bf16)Wnode[(size_t)(c * 32 + quad * 8 + j) * COUT +
                                       ot * 16 + l16];
#pragma unroll
            for (int mt = 0; mt < 2; ++mt)
                acc[mt][ot] = __builtin_amdgcn_mfma_f32_16x16x32_bf16(
                                  af[mt], bfr, acc[mt][ot], 0, 0, 0);
        }
    }

    // bias[o] = sum_d E[n][d] * bias_pool[d][o], per lane for o = ot*16+l16
    float en[DEMB];
#pragma unroll
    for (int d = 0; d < DEMB; ++d) en[d] = E[(size_t)n * DEMB + d];
#pragma unroll
    for (int ot = 0; ot < 4; ++ot) {
        float bv = 0.f;
        const int o = ot * 16 + l16;
#pragma unroll
        for (int d = 0; d < DEMB; ++d) bv += en[d] * bias_pool[d * COUT + o];
#pragma unroll
        for (int mt = 0; mt < 2; ++mt)
#pragma unroll
            for (int r = 0; r < 4; ++r) {
                const int b = mt * 16 + quad * 4 + r;
                out[((size_t)b * N_NODES + n) * COUT + o] = acc[mt][ot][r] + bv;
            }
    }
}

// ---------------------------------------------------------------------------
extern "C" void kernel_launch(void* const* d_in, const int* in_sizes, int n_in,
                              void* d_out, int out_size, void* d_ws, size_t ws_size,
                              hipStream_t stream) {
    (void)in_sizes; (void)n_in; (void)out_size; (void)ws_size;
    const float* x  = (const float*)d_in[0];
    const float* E  = (const float*)d_in[1];
    // d_in[2] = laplacian_mx, unused by the reference forward
    const float* Wp = (const float*)d_in[3];
    const float* bp = (const float*)d_in[4];
    float* out = (float*)d_out;

    char* ws = (char*)d_ws;
    __hip_bfloat16* A   = (__hip_bfloat16*)(ws);                 // 33554432 B
    __hip_bfloat16* Xt  = (__hip_bfloat16*)(ws + 33554432);      //  8388608 B
    __hip_bfloat16* Bt1 = (__hip_bfloat16*)(ws + 41943040);      //  8388608 B (X^T; reused as Y2)
    __hip_bfloat16* Y1  = (__hip_bfloat16*)(ws + 50331648);      //  8388608 B
    __hip_bfloat16* Y1t = (__hip_bfloat16*)(ws + 58720256);      //  8388608 B
    __hip_bfloat16* P   = (__hip_bfloat16*)(ws + 67108864);      // 33554432 B bf16 partials [4][4096][1024]
    __hip_bfloat16* Wn  = (__hip_bfloat16*)(ws + 67108864);      // 50331648 B (SAME region: P dead before gen_w)
    // total ws use: 117440512 B

    compute_A_kernel<<<N_NODES / 16, 256, 0, stream>>>(E, A);
    transpose_kernel<<<dim3(N_NODES / 64, BATCH), 256, 0, stream>>>(x, Xt, Bt1);
    // Y1 = A @ X : split-K=4 -> 1024 blocks (4/CU)
    gemm_splitk_kernel<<<dim3(NCOL / 128, N_NODES / 128, SPLITK), 256, 0, stream>>>(
        A, Bt1, P, N_NODES, NCOL, N_NODES);
    combine1_kernel<<<dim3(NCOL / 64, N_NODES / 64), 256, 0, stream>>>(
        P, Y1, Y1t, N_NODES, NCOL);
    // Y2 = 2*A@Y1 - X
    gemm_splitk_kernel<<<dim3(NCOL / 128, N_NODES / 128, SPLITK), 256, 0, stream>>>(
        A, Y1t, P, N_NODES, NCOL, N_NODES);
    combine2_kernel<<<dim3(N_NODES * NCOL / 4096), 256, 0, stream>>>(
        P, Xt, Bt1, N_NODES, NCOL);
    // gen_w AFTER combine2: Wn shares the P region
    gen_w_kernel<<<dim3(KIO / 256, N_NODES / 64), 256, 0, stream>>>(E, Wp, Wn);
    final_kernel<<<N_NODES / 4, 256, 0, stream>>>(Xt, Y1, Bt1, Wn, E, bp, out);
}

// Round 5
// 312.343 us; speedup vs baseline: 1.4473x; 1.1529x over previous
//
#include <hip/hip_runtime.h>
#include <hip/hip_bf16.h>

#define N_NODES 4096
#define BATCH   32
#define CIN     32
#define COUT    64
#define DEMB    16
#define NCOL    (BATCH * CIN)      // 1024 columns of the propagation GEMMs
#define KIO     (3 * CIN * COUT)   // 6144 generated-weight elements per node
#define SPLITK  3

typedef __bf16 bf16x8 __attribute__((ext_vector_type(8)));
typedef float  floatx4 __attribute__((ext_vector_type(4)));

__device__ inline void load_lds16(const void* g, void* l) {
    __builtin_amdgcn_global_load_lds(
        (const __attribute__((address_space(1))) void*)g,
        (__attribute__((address_space(3))) void*)l, 16, 0, 0);
}

// ---------------------------------------------------------------------------
// K0: U[n][m] = exp(relu(E[n].E[m])) (UNNORMALIZED, bf16) + invRow[n]=1/rowsum.
// softmax = diag(invRow) @ U; the inv[row] scale is folded into the GEMM
// combine epilogues (row-diagonal commutes through U@X). No LDS: every
// thread streams E columns straight from L2-resident E (256 KB).
// 512 blocks x 8 rows; each thread handles 16 columns.
// ---------------------------------------------------------------------------
__global__ __launch_bounds__(256) void compute_U_kernel(
        const float* __restrict__ E, __hip_bfloat16* __restrict__ U,
        float* __restrict__ invRow) {
    const int n0   = blockIdx.x * 8;
    const int t    = threadIdx.x;
    const int lane = t & 63, wave = t >> 6;
    __shared__ float red[4][8];

    float en[8][DEMB];                  // block's 8 rows of E (uniform)
#pragma unroll
    for (int r = 0; r < 8; ++r) {
        const float4* er = (const float4*)&E[(size_t)(n0 + r) * DEMB];
        const float4 a0 = er[0], a1 = er[1], a2 = er[2], a3 = er[3];
        en[r][ 0]=a0.x; en[r][ 1]=a0.y; en[r][ 2]=a0.z; en[r][ 3]=a0.w;
        en[r][ 4]=a1.x; en[r][ 5]=a1.y; en[r][ 6]=a1.z; en[r][ 7]=a1.w;
        en[r][ 8]=a2.x; en[r][ 9]=a2.y; en[r][10]=a2.z; en[r][11]=a2.w;
        en[r][12]=a3.x; en[r][13]=a3.y; en[r][14]=a3.z; en[r][15]=a3.w;
    }

    float sum[8] = {0.f, 0.f, 0.f, 0.f, 0.f, 0.f, 0.f, 0.f};

    for (int tile = 0; tile < 16; ++tile) {
        const int c = tile * 256 + t;
        const float4* em4 = (const float4*)&E[(size_t)c * DEMB];
        const float4 b0 = em4[0], b1 = em4[1], b2 = em4[2], b3 = em4[3];
        float em[DEMB];
        em[ 0]=b0.x; em[ 1]=b0.y; em[ 2]=b0.z; em[ 3]=b0.w;
        em[ 4]=b1.x; em[ 5]=b1.y; em[ 6]=b1.z; em[ 7]=b1.w;
        em[ 8]=b2.x; em[ 9]=b2.y; em[10]=b2.z; em[11]=b2.w;
        em[12]=b3.x; em[13]=b3.y; em[14]=b3.z; em[15]=b3.w;
#pragma unroll
        for (int r = 0; r < 8; ++r) {
            float dt = 0.f;
#pragma unroll
            for (int d = 0; d < DEMB; ++d) dt += en[r][d] * em[d];
            const float ev = __expf(fmaxf(dt, 0.f));   // exp(relu(.)), >= 0
            sum[r] += ev;
            U[(size_t)(n0 + r) * N_NODES + c] = __float2bfloat16(ev);
        }
    }
#pragma unroll
    for (int r = 0; r < 8; ++r)
#pragma unroll
        for (int off = 32; off > 0; off >>= 1) sum[r] += __shfl_xor(sum[r], off);
    if (lane == 0)
#pragma unroll
        for (int r = 0; r < 8; ++r) red[wave][r] = sum[r];
    __syncthreads();
    if (t < 8)
        invRow[n0 + t] = 1.0f / (red[0][t] + red[1][t] + red[2][t] + red[3][t]);
}

// ---------------------------------------------------------------------------
// K1: x[b][m][c] (fp32) -> Xt[m][b*32+c] (bf16) and Bt1[b*32+c][m] (bf16)
// ---------------------------------------------------------------------------
__global__ __launch_bounds__(256) void transpose_kernel(
        const float* __restrict__ x,
        __hip_bfloat16* __restrict__ Xt, __hip_bfloat16* __restrict__ Bt) {
    const int m0 = blockIdx.x * 64;
    const int b  = blockIdx.y;
    const int t  = threadIdx.x;
    __shared__ float tile[64][33];
    {
        const int ml = t >> 2, cg = (t & 3) * 8;
        const float* src = &x[((size_t)b * N_NODES + (m0 + ml)) * CIN + cg];
        const float4 r0 = *(const float4*)src;
        const float4 r1 = *(const float4*)(src + 4);
        tile[ml][cg+0] = r0.x; tile[ml][cg+1] = r0.y; tile[ml][cg+2] = r0.z; tile[ml][cg+3] = r0.w;
        tile[ml][cg+4] = r1.x; tile[ml][cg+5] = r1.y; tile[ml][cg+6] = r1.z; tile[ml][cg+7] = r1.w;
    }
    __syncthreads();
    {
        const int ml = t >> 2, cg = (t & 3) * 8;
        __hip_bfloat16* dst = &Xt[(size_t)(m0 + ml) * NCOL + b * CIN + cg];
#pragma unroll
        for (int j = 0; j < 8; ++j) dst[j] = __float2bfloat16(tile[ml][cg + j]);
    }
    {
        const int c = t >> 3, mg = (t & 7) * 8;
        __hip_bfloat16* dst = &Bt[(size_t)(b * CIN + c) * N_NODES + m0 + mg];
#pragma unroll
        for (int j = 0; j < 8; ++j) dst[j] = __float2bfloat16(tile[mg + j][c]);
    }
}

// ---------------------------------------------------------------------------
// K2: Wn[n][j] = sum_d E[n][d] * Wpool[d][j]   (j < 6144), bf16 out
// ---------------------------------------------------------------------------
__global__ __launch_bounds__(256) void gen_w_kernel(
        const float* __restrict__ E, const float* __restrict__ Wp,
        __hip_bfloat16* __restrict__ Wn) {
    const int jc = blockIdx.x * 256;
    const int nc = blockIdx.y * 64;
    const int t  = threadIdx.x;
    __shared__ float wp[DEMB][256];
    __shared__ float et[64][DEMB];
#pragma unroll
    for (int d = 0; d < DEMB; ++d) wp[d][t] = Wp[(size_t)d * KIO + jc + t];
    ((float4*)et)[t] = ((const float4*)&E[(size_t)nc * DEMB])[t];
    __syncthreads();
    float w[DEMB];
#pragma unroll
    for (int d = 0; d < DEMB; ++d) w[d] = wp[d][t];
    for (int nl = 0; nl < 64; ++nl) {
        float acc = 0.0f;
#pragma unroll
        for (int d = 0; d < DEMB; ++d) acc += et[nl][d] * w[d];
        Wn[(size_t)(nc + nl) * KIO + jc + t] = __float2bfloat16(acc);
    }
}

// ---------------------------------------------------------------------------
// K3: split-K GEMM. P[z][row][col] = sum_{k in slice z} A[row][k]*Bt[col][k]
// 128x128 tile, BK=32, SPLITK=3 -> 768 blocks (round-3's best-measured cfg).
// Partials stored bf16 (halves P traffic vs fp32).
// ---------------------------------------------------------------------------
__global__ __launch_bounds__(256) void gemm_splitk_kernel(
        const __hip_bfloat16* __restrict__ A,    // [M][K]
        const __hip_bfloat16* __restrict__ Bt,   // [NC][K]
        __hip_bfloat16* __restrict__ P,          // [SPLITK][M][NC] bf16 partials
        int M, int NC, int K) {
    const int t    = threadIdx.x;
    const int col0 = blockIdx.x * 128;
    const int row0 = blockIdx.y * 128;
    const int z    = blockIdx.z;
    const int iters = K >> 5;
    const int q = iters / SPLITK, rem = iters % SPLITK;
    const int it0 = z * q + (z < rem ? z : rem);
    const int it1 = it0 + q + (z < rem ? 1 : 0);

    __shared__ alignas(16) __hip_bfloat16 As[128 * 32];
    __shared__ alignas(16) __hip_bfloat16 Bs[128 * 32];
    const int lane = t & 63, wave = t >> 6;
    const int l16 = lane & 15, quad = lane >> 4;
    const int wrow = (wave >> 1) * 64, wcol = (wave & 1) * 64;

    floatx4 acc[4][4] = {};

    for (int it = it0; it < it1; ++it) {
        const int kb = it << 5;
        __syncthreads();
#pragma unroll
        for (int s = 0; s < 2; ++s) {
            const int e = s * 2048 + t * 8;
            const int r = e >> 5, ko = e & 31;
            load_lds16(&A [(size_t)(row0 + r) * K + kb + ko], &As[e]);
            load_lds16(&Bt[(size_t)(col0 + r) * K + kb + ko], &Bs[e]);
        }
        __syncthreads();
        bf16x8 af[4], bfr[4];
#pragma unroll
        for (int i = 0; i < 4; ++i)
            af[i]  = *(const bf16x8*)&As[(wrow + i * 16 + l16) * 32 + quad * 8];
#pragma unroll
        for (int i = 0; i < 4; ++i)
            bfr[i] = *(const bf16x8*)&Bs[(wcol + i * 16 + l16) * 32 + quad * 8];
#pragma unroll
        for (int i = 0; i < 4; ++i)
#pragma unroll
            for (int j = 0; j < 4; ++j)
                acc[i][j] = __builtin_amdgcn_mfma_f32_16x16x32_bf16(
                                af[i], bfr[j], acc[i][j], 0, 0, 0);
    }

    __hip_bfloat16* Pz = P + (size_t)z * M * NC;
#pragma unroll
    for (int i = 0; i < 4; ++i)
#pragma unroll
        for (int j = 0; j < 4; ++j)
#pragma unroll
            for (int r = 0; r < 4; ++r) {
                const int rg = row0 + wrow + i * 16 + quad * 4 + r;
                const int cg = col0 + wcol + j * 16 + l16;
                Pz[(size_t)rg * NC + cg] = __float2bfloat16(acc[i][j][r]);
            }
}

// ---------------------------------------------------------------------------
// K3b: combine1 -> Y1 = bf16(inv[row] * sum_z Pz), plus transposed Y1t
// ---------------------------------------------------------------------------
__global__ __launch_bounds__(256) void combine1_kernel(
        const __hip_bfloat16* __restrict__ P, const float* __restrict__ invRow,
        __hip_bfloat16* __restrict__ Y, __hip_bfloat16* __restrict__ Yt,
        int M, int NC) {
    const int c0 = blockIdx.x * 64, m0 = blockIdx.y * 64;
    const int t = threadIdx.x;
    __shared__ float tile[64][65];
    const size_t stride = (size_t)M * NC;
#pragma unroll
    for (int j = 0; j < 16; ++j) {
        const int lin = t + j * 256;
        const int r = lin >> 6, c = lin & 63;
        const size_t idx = (size_t)(m0 + r) * NC + c0 + c;
        float s = 0.f;
#pragma unroll
        for (int z = 0; z < SPLITK; ++z) s += __bfloat162float(P[idx + z * stride]);
        s *= invRow[m0 + r];
        tile[r][c] = s;
        Y[idx] = __float2bfloat16(s);
    }
    __syncthreads();
#pragma unroll
    for (int j = 0; j < 16; ++j) {
        const int lin = t + j * 256;
        const int c = lin >> 6, r = lin & 63;
        Yt[(size_t)(c0 + c) * M + m0 + r] = __float2bfloat16(tile[r][c]);
    }
}

// ---------------------------------------------------------------------------
// K3c: combine2 -> Y2 = bf16(2*inv[row]*sum_z Pz - Xt)  (Chebyshev T2)
// ---------------------------------------------------------------------------
__global__ __launch_bounds__(256) void combine2_kernel(
        const __hip_bfloat16* __restrict__ P, const float* __restrict__ invRow,
        const __hip_bfloat16* __restrict__ sub, __hip_bfloat16* __restrict__ Y2,
        int M, int NC) {
    const size_t stride = (size_t)M * NC;
    const size_t idx0 = (size_t)blockIdx.x * 4096 + threadIdx.x;
#pragma unroll
    for (int j = 0; j < 16; ++j) {
        const size_t idx = idx0 + (size_t)j * 256;
        float s = 0.f;
#pragma unroll
        for (int z = 0; z < SPLITK; ++z) s += __bfloat162float(P[idx + z * stride]);
        s *= invRow[idx >> 10];          // row = idx / NCOL (NCOL = 1024)
        Y2[idx] = __float2bfloat16(2.0f * s - __bfloat162float(sub[idx]));
    }
}

// ---------------------------------------------------------------------------
// K4: per-node grouped GEMM via MFMA. out[b][n][o] = sum_k G[b][k] W[k][o] + bias
// One wave per node, 4 nodes per block. C/D layout: row=quad*4+r, col=l16.
// ---------------------------------------------------------------------------
__global__ __launch_bounds__(256) void final_kernel(
        const __hip_bfloat16* __restrict__ Xt, const __hip_bfloat16* __restrict__ Y1,
        const __hip_bfloat16* __restrict__ Y2, const __hip_bfloat16* __restrict__ Wn,
        const float* __restrict__ E, const float* __restrict__ bias_pool,
        float* __restrict__ out) {
    const int t    = threadIdx.x;
    const int lane = t & 63, wave = t >> 6;
    const int l16  = lane & 15, quad = lane >> 4;
    const int n    = blockIdx.x * 4 + wave;

    const __hip_bfloat16* srcs[3] = {Xt, Y1, Y2};
    const __hip_bfloat16* Wnode = Wn + (size_t)n * KIO;

    floatx4 acc[2][4] = {};   // [mt][ot]

#pragma unroll
    for (int c = 0; c < 3; ++c) {
        bf16x8 af[2];
#pragma unroll
        for (int mt = 0; mt < 2; ++mt)
            af[mt] = *(const bf16x8*)&srcs[c][(size_t)n * NCOL +
                                              (mt * 16 + l16) * 32 + quad * 8];
#pragma unroll
        for (int ot = 0; ot < 4; ++ot) {
            bf16x8 bfr;
#pragma unroll
            for (int j = 0; j < 8; ++j)
                bfr[j] = (__bf16)Wnode[(size_t)(c * 32 + quad * 8 + j) * COUT +
                                       ot * 16 + l16];
#pragma unroll
            for (int mt = 0; mt < 2; ++mt)
                acc[mt][ot] = __builtin_amdgcn_mfma_f32_16x16x32_bf16(
                                  af[mt], bfr, acc[mt][ot], 0, 0, 0);
        }
    }

    float en[DEMB];
#pragma unroll
    for (int d = 0; d < DEMB; ++d) en[d] = E[(size_t)n * DEMB + d];
#pragma unroll
    for (int ot = 0; ot < 4; ++ot) {
        float bv = 0.f;
        const int o = ot * 16 + l16;
#pragma unroll
        for (int d = 0; d < DEMB; ++d) bv += en[d] * bias_pool[d * COUT + o];
#pragma unroll
        for (int mt = 0; mt < 2; ++mt)
#pragma unroll
            for (int r = 0; r < 4; ++r) {
                const int b = mt * 16 + quad * 4 + r;
                out[((size_t)b * N_NODES + n) * COUT + o] = acc[mt][ot][r] + bv;
            }
    }
}

// ---------------------------------------------------------------------------
extern "C" void kernel_launch(void* const* d_in, const int* in_sizes, int n_in,
                              void* d_out, int out_size, void* d_ws, size_t ws_size,
                              hipStream_t stream) {
    (void)in_sizes; (void)n_in; (void)out_size; (void)ws_size;
    const float* x  = (const float*)d_in[0];
    const float* E  = (const float*)d_in[1];
    // d_in[2] = laplacian_mx, unused by the reference forward
    const float* Wp = (const float*)d_in[3];
    const float* bp = (const float*)d_in[4];
    float* out = (float*)d_out;

    char* ws = (char*)d_ws;
    __hip_bfloat16* U   = (__hip_bfloat16*)(ws);                 // 33554432 B (unnormalized exp)
    __hip_bfloat16* Xt  = (__hip_bfloat16*)(ws + 33554432);      //  8388608 B
    __hip_bfloat16* Bt1 = (__hip_bfloat16*)(ws + 41943040);      //  8388608 B (X^T; reused as Y2)
    __hip_bfloat16* Y1  = (__hip_bfloat16*)(ws + 50331648);      //  8388608 B
    __hip_bfloat16* Y1t = (__hip_bfloat16*)(ws + 58720256);      //  8388608 B
    __hip_bfloat16* P   = (__hip_bfloat16*)(ws + 67108864);      // 25165824 B bf16 partials [3][4096][1024]
    float*       invRow = (float*)(ws + 67108864 + 25165824);    //    16384 B (dead before Wn written)
    __hip_bfloat16* Wn  = (__hip_bfloat16*)(ws + 67108864);      // 50331648 B (SAME region: P+invRow dead before gen_w)
    // total ws use: 117440512 B

    compute_U_kernel<<<N_NODES / 8, 256, 0, stream>>>(E, U, invRow);
    transpose_kernel<<<dim3(N_NODES / 64, BATCH), 256, 0, stream>>>(x, Xt, Bt1);
    // Y1 = inv * (U @ X) : split-K=3 -> 768 blocks
    gemm_splitk_kernel<<<dim3(NCOL / 128, N_NODES / 128, SPLITK), 256, 0, stream>>>(
        U, Bt1, P, N_NODES, NCOL, N_NODES);
    combine1_kernel<<<dim3(NCOL / 64, N_NODES / 64), 256, 0, stream>>>(
        P, invRow, Y1, Y1t, N_NODES, NCOL);
    // Y2 = 2*inv*(U @ Y1) - X
    gemm_splitk_kernel<<<dim3(NCOL / 128, N_NODES / 128, SPLITK), 256, 0, stream>>>(
        U, Y1t, P, N_NODES, NCOL, N_NODES);
    combine2_kernel<<<dim3(N_NODES * NCOL / 4096), 256, 0, stream>>>(
        P, invRow, Xt, Bt1, N_NODES, NCOL);
    // gen_w AFTER combine2: Wn shares the P/invRow region
    gen_w_kernel<<<dim3(KIO / 256, N_NODES / 64), 256, 0, stream>>>(E, Wp, Wn);
    final_kernel<<<N_NODES / 4, 256, 0, stream>>>(Xt, Y1, Bt1, Wn, E, bp, out);
}

// Round 6
// 310.036 us; speedup vs baseline: 1.4581x; 1.0074x over previous
//
#include <hip/hip_runtime.h>
#include <hip/hip_bf16.h>

#define N_NODES 4096
#define BATCH   32
#define CIN     32
#define COUT    64
#define DEMB    16
#define NCOL    (BATCH * CIN)      // 1024 columns of the propagation GEMMs
#define KIO     (3 * CIN * COUT)   // 6144 generated-weight elements per node
#define SPLITK  3

typedef __bf16 bf16x8 __attribute__((ext_vector_type(8)));
typedef float  floatx4 __attribute__((ext_vector_type(4)));

__device__ inline void load_lds16(const void* g, void* l) {
    __builtin_amdgcn_global_load_lds(
        (const __attribute__((address_space(1))) void*)g,
        (__attribute__((address_space(3))) void*)l, 16, 0, 0);
}

// ---------------------------------------------------------------------------
// K0: U[n][m] = exp(relu(E[n].E[m])) (UNNORMALIZED, bf16) + invRow[n]=1/rowsum.
// softmax = diag(invRow) @ U; inv folded into GEMM combine epilogues.
// ---------------------------------------------------------------------------
__global__ __launch_bounds__(256) void compute_U_kernel(
        const float* __restrict__ E, __hip_bfloat16* __restrict__ U,
        float* __restrict__ invRow) {
    const int n0   = blockIdx.x * 8;
    const int t    = threadIdx.x;
    const int lane = t & 63, wave = t >> 6;
    __shared__ float red[4][8];

    float en[8][DEMB];
#pragma unroll
    for (int r = 0; r < 8; ++r) {
        const float4* er = (const float4*)&E[(size_t)(n0 + r) * DEMB];
        const float4 a0 = er[0], a1 = er[1], a2 = er[2], a3 = er[3];
        en[r][ 0]=a0.x; en[r][ 1]=a0.y; en[r][ 2]=a0.z; en[r][ 3]=a0.w;
        en[r][ 4]=a1.x; en[r][ 5]=a1.y; en[r][ 6]=a1.z; en[r][ 7]=a1.w;
        en[r][ 8]=a2.x; en[r][ 9]=a2.y; en[r][10]=a2.z; en[r][11]=a2.w;
        en[r][12]=a3.x; en[r][13]=a3.y; en[r][14]=a3.z; en[r][15]=a3.w;
    }

    float sum[8] = {0.f, 0.f, 0.f, 0.f, 0.f, 0.f, 0.f, 0.f};

    for (int tile = 0; tile < 16; ++tile) {
        const int c = tile * 256 + t;
        const float4* em4 = (const float4*)&E[(size_t)c * DEMB];
        const float4 b0 = em4[0], b1 = em4[1], b2 = em4[2], b3 = em4[3];
        float em[DEMB];
        em[ 0]=b0.x; em[ 1]=b0.y; em[ 2]=b0.z; em[ 3]=b0.w;
        em[ 4]=b1.x; em[ 5]=b1.y; em[ 6]=b1.z; em[ 7]=b1.w;
        em[ 8]=b2.x; em[ 9]=b2.y; em[10]=b2.z; em[11]=b2.w;
        em[12]=b3.x; em[13]=b3.y; em[14]=b3.z; em[15]=b3.w;
#pragma unroll
        for (int r = 0; r < 8; ++r) {
            float dt = 0.f;
#pragma unroll
            for (int d = 0; d < DEMB; ++d) dt += en[r][d] * em[d];
            const float ev = __expf(fmaxf(dt, 0.f));
            sum[r] += ev;
            U[(size_t)(n0 + r) * N_NODES + c] = __float2bfloat16(ev);
        }
    }
#pragma unroll
    for (int r = 0; r < 8; ++r)
#pragma unroll
        for (int off = 32; off > 0; off >>= 1) sum[r] += __shfl_xor(sum[r], off);
    if (lane == 0)
#pragma unroll
        for (int r = 0; r < 8; ++r) red[wave][r] = sum[r];
    __syncthreads();
    if (t < 8)
        invRow[n0 + t] = 1.0f / (red[0][t] + red[1][t] + red[2][t] + red[3][t]);
}

// ---------------------------------------------------------------------------
// K1: x[b][m][c] (fp32) -> Xt[m][b*32+c] (bf16) and Bt1[b*32+c][m] (bf16)
// ---------------------------------------------------------------------------
__global__ __launch_bounds__(256) void transpose_kernel(
        const float* __restrict__ x,
        __hip_bfloat16* __restrict__ Xt, __hip_bfloat16* __restrict__ Bt) {
    const int m0 = blockIdx.x * 64;
    const int b  = blockIdx.y;
    const int t  = threadIdx.x;
    __shared__ float tile[64][33];
    {
        const int ml = t >> 2, cg = (t & 3) * 8;
        const float* src = &x[((size_t)b * N_NODES + (m0 + ml)) * CIN + cg];
        const float4 r0 = *(const float4*)src;
        const float4 r1 = *(const float4*)(src + 4);
        tile[ml][cg+0] = r0.x; tile[ml][cg+1] = r0.y; tile[ml][cg+2] = r0.z; tile[ml][cg+3] = r0.w;
        tile[ml][cg+4] = r1.x; tile[ml][cg+5] = r1.y; tile[ml][cg+6] = r1.z; tile[ml][cg+7] = r1.w;
    }
    __syncthreads();
    {
        const int ml = t >> 2, cg = (t & 3) * 8;
        __hip_bfloat16* dst = &Xt[(size_t)(m0 + ml) * NCOL + b * CIN + cg];
#pragma unroll
        for (int j = 0; j < 8; ++j) dst[j] = __float2bfloat16(tile[ml][cg + j]);
    }
    {
        const int c = t >> 3, mg = (t & 7) * 8;
        __hip_bfloat16* dst = &Bt[(size_t)(b * CIN + c) * N_NODES + m0 + mg];
#pragma unroll
        for (int j = 0; j < 8; ++j) dst[j] = __float2bfloat16(tile[mg + j][c]);
    }
}

// ---------------------------------------------------------------------------
// K2: generated weights, stored PRE-SWIZZLED for final_kernel's MFMA B-frags:
//   Wn[n][c][ot][l16][quad*8+j] = sum_d E[n][d]*Wp[d][(c*32+quad*8+j)*64+ot*16+l16]
// Thread t of block (c, n-group): quad=t&3, l16=(t>>2)&15, ot=t>>6; holds
// w[16][8] in regs (one stride-64 gather from L2-resident Wp), loops 16 nodes
// with wave-uniform scalar E loads, stores 16 B contiguous. No LDS.
// ---------------------------------------------------------------------------
__global__ __launch_bounds__(256) void gen_w_kernel(
        const float* __restrict__ E, const float* __restrict__ Wp,
        __hip_bfloat16* __restrict__ Wn) {
    const int c  = blockIdx.x;           // cheb index 0..2
    const int n0 = blockIdx.y * 16;      // node group
    const int t  = threadIdx.x;
    const int quad = t & 3, l16 = (t >> 2) & 15, ot = t >> 6;
    const int base = (c * 32 + quad * 8) * 64 + ot * 16 + l16;  // original col

    float w[DEMB][8];
#pragma unroll
    for (int d = 0; d < DEMB; ++d)
#pragma unroll
        for (int j = 0; j < 8; ++j)
            w[d][j] = Wp[(size_t)d * KIO + base + j * 64];

    for (int n = 0; n < 16; ++n) {
        float acc[8] = {};
#pragma unroll
        for (int d = 0; d < DEMB; ++d) {
            const float ed = E[(size_t)(n0 + n) * DEMB + d];
#pragma unroll
            for (int j = 0; j < 8; ++j) acc[j] += ed * w[d][j];
        }
        __hip_bfloat16 o8[8];
#pragma unroll
        for (int j = 0; j < 8; ++j) o8[j] = __float2bfloat16(acc[j]);
        *(ulonglong2*)&Wn[((size_t)(n0 + n) * 3 + c) * 2048 + t * 8] =
            *(const ulonglong2*)o8;
    }
}

// ---------------------------------------------------------------------------
// K3: split-K GEMM, 128x128 tile, BK=64 (half the barriers of BK=32), XOR
// granule swizzle c' = c ^ (r&7) keeps LDS bank slots even despite the 128 B
// row stride (swizzle redirects the GLOBAL source; LDS dest stays the
// contiguous lane*16 pattern global_load_lds requires).
// Grid (M/128, NC/128, SPLITK): blockIdx.x = row-strip so the 8 blocks
// sharing an A-strip land on one XCD (linear%8 = x%8) -> A fetched once/L2.
// ---------------------------------------------------------------------------
__global__ __launch_bounds__(256) void gemm_splitk_kernel(
        const __hip_bfloat16* __restrict__ A,    // [M][K]
        const __hip_bfloat16* __restrict__ Bt,   // [NC][K]
        __hip_bfloat16* __restrict__ P,          // [SPLITK][M][NC] bf16 partials
        int M, int NC, int K) {
    const int t    = threadIdx.x;
    const int row0 = blockIdx.x * 128;
    const int col0 = blockIdx.y * 128;
    const int z    = blockIdx.z;
    const int iters = K >> 6;                  // BK=64
    const int q = iters / SPLITK, rem = iters % SPLITK;
    const int it0 = z * q + (z < rem ? z : rem);
    const int it1 = it0 + q + (z < rem ? 1 : 0);

    __shared__ alignas(16) __hip_bfloat16 As[128 * 64];
    __shared__ alignas(16) __hip_bfloat16 Bs[128 * 64];
    const int lane = t & 63, wave = t >> 6;
    const int l16 = lane & 15, quad = lane >> 4;
    const int wrow = (wave >> 1) * 64, wcol = (wave & 1) * 64;
    const int xr = l16 & 7;

    floatx4 acc[4][4] = {};

    for (int it = it0; it < it1; ++it) {
        const int kb = it << 6;
        __syncthreads();
#pragma unroll
        for (int s = 0; s < 4; ++s) {
            const int gi = s * 256 + t;          // 16B granule index 0..1023
            const int r  = gi >> 3;              // tile row 0..127
            const int cg = (gi & 7) ^ (r & 7);   // swizzled global granule col
            load_lds16(&A [(size_t)(row0 + r) * K + kb + cg * 8], &As[gi * 8]);
            load_lds16(&Bt[(size_t)(col0 + r) * K + kb + cg * 8], &Bs[gi * 8]);
        }
        __syncthreads();
#pragma unroll
        for (int ks = 0; ks < 2; ++ks) {
            bf16x8 af[4], bfr[4];
#pragma unroll
            for (int i = 0; i < 4; ++i)
                af[i]  = *(const bf16x8*)&As[(wrow + i * 16 + l16) * 64 +
                                             (((ks * 4 + quad) ^ xr) * 8)];
#pragma unroll
            for (int i = 0; i < 4; ++i)
                bfr[i] = *(const bf16x8*)&Bs[(wcol + i * 16 + l16) * 64 +
                                             (((ks * 4 + quad) ^ xr) * 8)];
#pragma unroll
            for (int i = 0; i < 4; ++i)
#pragma unroll
                for (int j = 0; j < 4; ++j)
                    acc[i][j] = __builtin_amdgcn_mfma_f32_16x16x32_bf16(
                                    af[i], bfr[j], acc[i][j], 0, 0, 0);
        }
    }

    __hip_bfloat16* Pz = P + (size_t)z * M * NC;
#pragma unroll
    for (int i = 0; i < 4; ++i)
#pragma unroll
        for (int j = 0; j < 4; ++j)
#pragma unroll
            for (int r = 0; r < 4; ++r) {
                const int rg = row0 + wrow + i * 16 + quad * 4 + r;
                const int cg = col0 + wcol + j * 16 + l16;
                Pz[(size_t)rg * NC + cg] = __float2bfloat16(acc[i][j][r]);
            }
}

// ---------------------------------------------------------------------------
// K3b: combine1 -> Y1 = bf16(inv[row] * sum_z Pz), plus transposed Y1t
// ---------------------------------------------------------------------------
__global__ __launch_bounds__(256) void combine1_kernel(
        const __hip_bfloat16* __restrict__ P, const float* __restrict__ invRow,
        __hip_bfloat16* __restrict__ Y, __hip_bfloat16* __restrict__ Yt,
        int M, int NC) {
    const int c0 = blockIdx.x * 64, m0 = blockIdx.y * 64;
    const int t = threadIdx.x;
    __shared__ float tile[64][65];
    const size_t stride = (size_t)M * NC;
#pragma unroll
    for (int j = 0; j < 16; ++j) {
        const int lin = t + j * 256;
        const int r = lin >> 6, c = lin & 63;
        const size_t idx = (size_t)(m0 + r) * NC + c0 + c;
        float s = 0.f;
#pragma unroll
        for (int z = 0; z < SPLITK; ++z) s += __bfloat162float(P[idx + z * stride]);
        s *= invRow[m0 + r];
        tile[r][c] = s;
        Y[idx] = __float2bfloat16(s);
    }
    __syncthreads();
#pragma unroll
    for (int j = 0; j < 16; ++j) {
        const int lin = t + j * 256;
        const int c = lin >> 6, r = lin & 63;
        Yt[(size_t)(c0 + c) * M + m0 + r] = __float2bfloat16(tile[r][c]);
    }
}

// ---------------------------------------------------------------------------
// K3c: combine2 -> Y2 = bf16(2*inv[row]*sum_z Pz - Xt)  (Chebyshev T2)
// ---------------------------------------------------------------------------
__global__ __launch_bounds__(256) void combine2_kernel(
        const __hip_bfloat16* __restrict__ P, const float* __restrict__ invRow,
        const __hip_bfloat16* __restrict__ sub, __hip_bfloat16* __restrict__ Y2,
        int M, int NC) {
    const size_t stride = (size_t)M * NC;
    const size_t idx0 = (size_t)blockIdx.x * 4096 + threadIdx.x;
#pragma unroll
    for (int j = 0; j < 16; ++j) {
        const size_t idx = idx0 + (size_t)j * 256;
        float s = 0.f;
#pragma unroll
        for (int z = 0; z < SPLITK; ++z) s += __bfloat162float(P[idx + z * stride]);
        s *= invRow[idx >> 10];          // row = idx / NCOL (NCOL = 1024)
        Y2[idx] = __float2bfloat16(2.0f * s - __bfloat162float(sub[idx]));
    }
}

// ---------------------------------------------------------------------------
// K4: per-node grouped GEMM via MFMA. out[b][n][o] = sum_k G[b][k] W[k][o] + bias
// B-frags read the pre-swizzled Wn: 16 B contiguous per lane, 1 KB per wave.
// One wave per node, 4 nodes per block. C/D layout: row=quad*4+r, col=l16.
// ---------------------------------------------------------------------------
__global__ __launch_bounds__(256) void final_kernel(
        const __hip_bfloat16* __restrict__ Xt, const __hip_bfloat16* __restrict__ Y1,
        const __hip_bfloat16* __restrict__ Y2, const __hip_bfloat16* __restrict__ Wn,
        const float* __restrict__ E, const float* __restrict__ bias_pool,
        float* __restrict__ out) {
    const int t    = threadIdx.x;
    const int lane = t & 63, wave = t >> 6;
    const int l16  = lane & 15, quad = lane >> 4;
    const int n    = blockIdx.x * 4 + wave;

    const __hip_bfloat16* srcs[3] = {Xt, Y1, Y2};
    const __hip_bfloat16* Wnode = Wn + (size_t)n * KIO;   // [c][ot][l16][quad*8+j]

    floatx4 acc[2][4] = {};   // [mt][ot]

#pragma unroll
    for (int c = 0; c < 3; ++c) {
        bf16x8 af[2];
#pragma unroll
        for (int mt = 0; mt < 2; ++mt)
            af[mt] = *(const bf16x8*)&srcs[c][(size_t)n * NCOL +
                                              (mt * 16 + l16) * 32 + quad * 8];
#pragma unroll
        for (int ot = 0; ot < 4; ++ot) {
            const bf16x8 bfr = *(const bf16x8*)&Wnode[(size_t)c * 2048 +
                                                      ot * 512 + l16 * 32 + quad * 8];
#pragma unroll
            for (int mt = 0; mt < 2; ++mt)
                acc[mt][ot] = __builtin_amdgcn_mfma_f32_16x16x32_bf16(
                                  af[mt], bfr, acc[mt][ot], 0, 0, 0);
        }
    }

    float en[DEMB];
#pragma unroll
    for (int d = 0; d < DEMB; ++d) en[d] = E[(size_t)n * DEMB + d];
#pragma unroll
    for (int ot = 0; ot < 4; ++ot) {
        float bv = 0.f;
        const int o = ot * 16 + l16;
#pragma unroll
        for (int d = 0; d < DEMB; ++d) bv += en[d] * bias_pool[d * COUT + o];
#pragma unroll
        for (int mt = 0; mt < 2; ++mt)
#pragma unroll
            for (int r = 0; r < 4; ++r) {
                const int b = mt * 16 + quad * 4 + r;
                out[((size_t)b * N_NODES + n) * COUT + o] = acc[mt][ot][r] + bv;
            }
    }
}

// ---------------------------------------------------------------------------
extern "C" void kernel_launch(void* const* d_in, const int* in_sizes, int n_in,
                              void* d_out, int out_size, void* d_ws, size_t ws_size,
                              hipStream_t stream) {
    (void)in_sizes; (void)n_in; (void)out_size; (void)ws_size;
    const float* x  = (const float*)d_in[0];
    const float* E  = (const float*)d_in[1];
    // d_in[2] = laplacian_mx, unused by the reference forward
    const float* Wp = (const float*)d_in[3];
    const float* bp = (const float*)d_in[4];
    float* out = (float*)d_out;

    char* ws = (char*)d_ws;
    __hip_bfloat16* U   = (__hip_bfloat16*)(ws);                 // 33554432 B (unnormalized exp)
    __hip_bfloat16* Xt  = (__hip_bfloat16*)(ws + 33554432);      //  8388608 B
    __hip_bfloat16* Bt1 = (__hip_bfloat16*)(ws + 41943040);      //  8388608 B (X^T; reused as Y2)
    __hip_bfloat16* Y1  = (__hip_bfloat16*)(ws + 50331648);      //  8388608 B
    __hip_bfloat16* Y1t = (__hip_bfloat16*)(ws + 58720256);      //  8388608 B
    __hip_bfloat16* P   = (__hip_bfloat16*)(ws + 67108864);      // 25165824 B bf16 partials [3][4096][1024]
    float*       invRow = (float*)(ws + 67108864 + 25165824);    //    16384 B (dead before Wn written)
    __hip_bfloat16* Wn  = (__hip_bfloat16*)(ws + 67108864);      // 50331648 B (SAME region: P+invRow dead before gen_w)
    // total ws use: 117440512 B

    compute_U_kernel<<<N_NODES / 8, 256, 0, stream>>>(E, U, invRow);
    transpose_kernel<<<dim3(N_NODES / 64, BATCH), 256, 0, stream>>>(x, Xt, Bt1);
    // Y1 = inv * (U @ X) : grid x = row-strip (XCD-co-locates A-strip sharers)
    gemm_splitk_kernel<<<dim3(N_NODES / 128, NCOL / 128, SPLITK), 256, 0, stream>>>(
        U, Bt1, P, N_NODES, NCOL, N_NODES);
    combine1_kernel<<<dim3(NCOL / 64, N_NODES / 64), 256, 0, stream>>>(
        P, invRow, Y1, Y1t, N_NODES, NCOL);
    // Y2 = 2*inv*(U @ Y1) - X
    gemm_splitk_kernel<<<dim3(N_NODES / 128, NCOL / 128, SPLITK), 256, 0, stream>>>(
        U, Y1t, P, N_NODES, NCOL, N_NODES);
    combine2_kernel<<<dim3(N_NODES * NCOL / 4096), 256, 0, stream>>>(
        P, invRow, Xt, Bt1, N_NODES, NCOL);
    // gen_w AFTER combine2: Wn shares the P/invRow region
    gen_w_kernel<<<dim3(3, N_NODES / 16), 256, 0, stream>>>(E, Wp, Wn);
    final_kernel<<<N_NODES / 4, 256, 0, stream>>>(Xt, Y1, Bt1, Wn, E, bp, out);
}

// Round 8
// 283.782 us; speedup vs baseline: 1.5930x; 1.0925x over previous
//
#include <hip/hip_runtime.h>
#include <hip/hip_bf16.h>

#define N_NODES 4096
#define BATCH   32
#define CIN     32
#define COUT    64
#define DEMB    16
#define NCOL    (BATCH * CIN)      // 1024 columns of the propagation GEMMs
#define KIO     (3 * CIN * COUT)   // 6144 generated-weight elements per node
#define SPLITK  3

typedef __bf16 bf16x8 __attribute__((ext_vector_type(8)));
typedef float  floatx4 __attribute__((ext_vector_type(4)));

__device__ inline void load_lds16(const void* g, void* l) {
    __builtin_amdgcn_global_load_lds(
        (const __attribute__((address_space(1))) void*)g,
        (__attribute__((address_space(3))) void*)l, 16, 0, 0);
}

// ---------------------------------------------------------------------------
// K0: U[n][m] = exp(relu(E[n].E[m])) (UNNORMALIZED, bf16) + invRow[n]=1/rowsum.
// softmax = diag(invRow) @ U; inv folded into GEMM combine epilogues.
// (round-5/6 version, verbatim — passed post-timing twice)
// ---------------------------------------------------------------------------
__global__ __launch_bounds__(256) void compute_U_kernel(
        const float* __restrict__ E, __hip_bfloat16* __restrict__ U,
        float* __restrict__ invRow) {
    const int n0   = blockIdx.x * 8;
    const int t    = threadIdx.x;
    const int lane = t & 63, wave = t >> 6;
    __shared__ float red[4][8];

    float en[8][DEMB];
#pragma unroll
    for (int r = 0; r < 8; ++r) {
        const float4* er = (const float4*)&E[(size_t)(n0 + r) * DEMB];
        const float4 a0 = er[0], a1 = er[1], a2 = er[2], a3 = er[3];
        en[r][ 0]=a0.x; en[r][ 1]=a0.y; en[r][ 2]=a0.z; en[r][ 3]=a0.w;
        en[r][ 4]=a1.x; en[r][ 5]=a1.y; en[r][ 6]=a1.z; en[r][ 7]=a1.w;
        en[r][ 8]=a2.x; en[r][ 9]=a2.y; en[r][10]=a2.z; en[r][11]=a2.w;
        en[r][12]=a3.x; en[r][13]=a3.y; en[r][14]=a3.z; en[r][15]=a3.w;
    }

    float sum[8] = {0.f, 0.f, 0.f, 0.f, 0.f, 0.f, 0.f, 0.f};

    for (int tile = 0; tile < 16; ++tile) {
        const int c = tile * 256 + t;
        const float4* em4 = (const float4*)&E[(size_t)c * DEMB];
        const float4 b0 = em4[0], b1 = em4[1], b2 = em4[2], b3 = em4[3];
        float em[DEMB];
        em[ 0]=b0.x; em[ 1]=b0.y; em[ 2]=b0.z; em[ 3]=b0.w;
        em[ 4]=b1.x; em[ 5]=b1.y; em[ 6]=b1.z; em[ 7]=b1.w;
        em[ 8]=b2.x; em[ 9]=b2.y; em[10]=b2.z; em[11]=b2.w;
        em[12]=b3.x; em[13]=b3.y; em[14]=b3.z; em[15]=b3.w;
#pragma unroll
        for (int r = 0; r < 8; ++r) {
            float dt = 0.f;
#pragma unroll
            for (int d = 0; d < DEMB; ++d) dt += en[r][d] * em[d];
            const float ev = __expf(fmaxf(dt, 0.f));
            sum[r] += ev;
            U[(size_t)(n0 + r) * N_NODES + c] = __float2bfloat16(ev);
        }
    }
#pragma unroll
    for (int r = 0; r < 8; ++r)
#pragma unroll
        for (int off = 32; off > 0; off >>= 1) sum[r] += __shfl_xor(sum[r], off);
    if (lane == 0)
#pragma unroll
        for (int r = 0; r < 8; ++r) red[wave][r] = sum[r];
    __syncthreads();
    if (t < 8)
        invRow[n0 + t] = 1.0f / (red[0][t] + red[1][t] + red[2][t] + red[3][t]);
}

// ---------------------------------------------------------------------------
// K1: x[b][m][c] (fp32) -> Xt[m][b*32+c] (bf16) and Bt1[b*32+c][m] (bf16)
// ---------------------------------------------------------------------------
__global__ __launch_bounds__(256) void transpose_kernel(
        const float* __restrict__ x,
        __hip_bfloat16* __restrict__ Xt, __hip_bfloat16* __restrict__ Bt) {
    const int m0 = blockIdx.x * 64;
    const int b  = blockIdx.y;
    const int t  = threadIdx.x;
    __shared__ float tile[64][33];
    {
        const int ml = t >> 2, cg = (t & 3) * 8;
        const float* src = &x[((size_t)b * N_NODES + (m0 + ml)) * CIN + cg];
        const float4 r0 = *(const float4*)src;
        const float4 r1 = *(const float4*)(src + 4);
        tile[ml][cg+0] = r0.x; tile[ml][cg+1] = r0.y; tile[ml][cg+2] = r0.z; tile[ml][cg+3] = r0.w;
        tile[ml][cg+4] = r1.x; tile[ml][cg+5] = r1.y; tile[ml][cg+6] = r1.z; tile[ml][cg+7] = r1.w;
    }
    __syncthreads();
    {
        const int ml = t >> 2, cg = (t & 3) * 8;
        __hip_bfloat16* dst = &Xt[(size_t)(m0 + ml) * NCOL + b * CIN + cg];
#pragma unroll
        for (int j = 0; j < 8; ++j) dst[j] = __float2bfloat16(tile[ml][cg + j]);
    }
    {
        const int c = t >> 3, mg = (t & 7) * 8;
        __hip_bfloat16* dst = &Bt[(size_t)(b * CIN + c) * N_NODES + m0 + mg];
#pragma unroll
        for (int j = 0; j < 8; ++j) dst[j] = __float2bfloat16(tile[mg + j][c]);
    }
}

// ---------------------------------------------------------------------------
// K2 v4: generated weights into the SWIZZLED layout final_kernel reads:
//   dest[n][c*2048 + ot*512 + l16*32 + kk] = sum_d E[n][d]*Wp[d][(c*32+kk)*64+ot*16+l16]
// Structure = round-5's PASSING gen_w (LDS-staged E rows, per-thread w[16],
// 64-node inner loop) with occupancy-first grid (24,64)=1536 blocks (~6/CU)
// and lane->kk mapping so swizzled stores are contiguous 64 B runs.
// et[nl][d] reads are wave-uniform -> LDS broadcast (conflict-free).
// ---------------------------------------------------------------------------
__global__ __launch_bounds__(256) void gen_w_kernel(
        const float* __restrict__ E, const float* __restrict__ Wp,
        __hip_bfloat16* __restrict__ Wn) {
    const int c   = blockIdx.x >> 3;          // cheb index 0..2
    const int oo0 = (blockIdx.x & 7) * 8;     // output-col group base
    const int nc  = blockIdx.y * 64;          // node group
    const int t   = threadIdx.x;
    const int kk  = t & 31;                   // within-c row index 0..31
    const int oo  = oo0 + (t >> 5);           // output col 0..63

    __shared__ float et[64][DEMB];            // 4 KB: 64 E rows
    ((float4*)et)[t] = ((const float4*)&E[(size_t)nc * DEMB])[t];
    __syncthreads();

    const int srccol = (c * 32 + kk) * 64 + oo;
    float w[DEMB];
#pragma unroll
    for (int d = 0; d < DEMB; ++d) w[d] = Wp[(size_t)d * KIO + srccol];

    const int dstoff = c * 2048 + (oo >> 4) * 512 + (oo & 15) * 32 + kk;
    for (int nl = 0; nl < 64; ++nl) {
        float acc = 0.0f;
#pragma unroll
        for (int d = 0; d < DEMB; ++d) acc += et[nl][d] * w[d];
        Wn[(size_t)(nc + nl) * KIO + dstoff] = __float2bfloat16(acc);
    }
}

// ---------------------------------------------------------------------------
// K3: split-K GEMM, 128x128 tile, BK=64, XOR granule swizzle (bank-even LDS),
// grid x = row-strip (XCD-co-locates A-strip sharers). SPLITK=3 -> 768 blocks.
// ---------------------------------------------------------------------------
__global__ __launch_bounds__(256) void gemm_splitk_kernel(
        const __hip_bfloat16* __restrict__ A,    // [M][K]
        const __hip_bfloat16* __restrict__ Bt,   // [NC][K]
        __hip_bfloat16* __restrict__ P,          // [SPLITK][M][NC] bf16 partials
        int M, int NC, int K) {
    const int t    = threadIdx.x;
    const int row0 = blockIdx.x * 128;
    const int col0 = blockIdx.y * 128;
    const int z    = blockIdx.z;
    const int iters = K >> 6;                  // BK=64
    const int q = iters / SPLITK, rem = iters % SPLITK;
    const int it0 = z * q + (z < rem ? z : rem);
    const int it1 = it0 + q + (z < rem ? 1 : 0);

    __shared__ alignas(16) __hip_bfloat16 As[128 * 64];
    __shared__ alignas(16) __hip_bfloat16 Bs[128 * 64];
    const int lane = t & 63, wave = t >> 6;
    const int l16 = lane & 15, quad = lane >> 4;
    const int wrow = (wave >> 1) * 64, wcol = (wave & 1) * 64;
    const int xr = l16 & 7;

    floatx4 acc[4][4] = {};

    for (int it = it0; it < it1; ++it) {
        const int kb = it << 6;
        __syncthreads();
#pragma unroll
        for (int s = 0; s < 4; ++s) {
            const int gi = s * 256 + t;          // 16B granule index 0..1023
            const int r  = gi >> 3;              // tile row 0..127
            const int cg = (gi & 7) ^ (r & 7);   // swizzled global granule col
            load_lds16(&A [(size_t)(row0 + r) * K + kb + cg * 8], &As[gi * 8]);
            load_lds16(&Bt[(size_t)(col0 + r) * K + kb + cg * 8], &Bs[gi * 8]);
        }
        __syncthreads();
#pragma unroll
        for (int ks = 0; ks < 2; ++ks) {
            bf16x8 af[4], bfr[4];
#pragma unroll
            for (int i = 0; i < 4; ++i)
                af[i]  = *(const bf16x8*)&As[(wrow + i * 16 + l16) * 64 +
                                             (((ks * 4 + quad) ^ xr) * 8)];
#pragma unroll
            for (int i = 0; i < 4; ++i)
                bfr[i] = *(const bf16x8*)&Bs[(wcol + i * 16 + l16) * 64 +
                                             (((ks * 4 + quad) ^ xr) * 8)];
#pragma unroll
            for (int i = 0; i < 4; ++i)
#pragma unroll
                for (int j = 0; j < 4; ++j)
                    acc[i][j] = __builtin_amdgcn_mfma_f32_16x16x32_bf16(
                                    af[i], bfr[j], acc[i][j], 0, 0, 0);
        }
    }

    __hip_bfloat16* Pz = P + (size_t)z * M * NC;
#pragma unroll
    for (int i = 0; i < 4; ++i)
#pragma unroll
        for (int j = 0; j < 4; ++j)
#pragma unroll
            for (int r = 0; r < 4; ++r) {
                const int rg = row0 + wrow + i * 16 + quad * 4 + r;
                const int cg = col0 + wcol + j * 16 + l16;
                Pz[(size_t)rg * NC + cg] = __float2bfloat16(acc[i][j][r]);
            }
}

// ---------------------------------------------------------------------------
// K3b: combine1 -> Y1 = bf16(inv[row] * sum_z Pz), plus transposed Y1t
// ---------------------------------------------------------------------------
__global__ __launch_bounds__(256) void combine1_kernel(
        const __hip_bfloat16* __restrict__ P, const float* __restrict__ invRow,
        __hip_bfloat16* __restrict__ Y, __hip_bfloat16* __restrict__ Yt,
        int M, int NC) {
    const int c0 = blockIdx.x * 64, m0 = blockIdx.y * 64;
    const int t = threadIdx.x;
    __shared__ float tile[64][65];
    const size_t stride = (size_t)M * NC;
#pragma unroll
    for (int j = 0; j < 16; ++j) {
        const int lin = t + j * 256;
        const int r = lin >> 6, c = lin & 63;
        const size_t idx = (size_t)(m0 + r) * NC + c0 + c;
        float s = 0.f;
#pragma unroll
        for (int z = 0; z < SPLITK; ++z) s += __bfloat162float(P[idx + z * stride]);
        s *= invRow[m0 + r];
        tile[r][c] = s;
        Y[idx] = __float2bfloat16(s);
    }
    __syncthreads();
#pragma unroll
    for (int j = 0; j < 16; ++j) {
        const int lin = t + j * 256;
        const int c = lin >> 6, r = lin & 63;
        Yt[(size_t)(c0 + c) * M + m0 + r] = __float2bfloat16(tile[r][c]);
    }
}

// ---------------------------------------------------------------------------
// K3c: combine2 -> Y2 = bf16(2*inv[row]*sum_z Pz - Xt)  (Chebyshev T2)
// ---------------------------------------------------------------------------
__global__ __launch_bounds__(256) void combine2_kernel(
        const __hip_bfloat16* __restrict__ P, const float* __restrict__ invRow,
        const __hip_bfloat16* __restrict__ sub, __hip_bfloat16* __restrict__ Y2,
        int M, int NC) {
    const size_t stride = (size_t)M * NC;
    const size_t idx0 = (size_t)blockIdx.x * 4096 + threadIdx.x;
#pragma unroll
    for (int j = 0; j < 16; ++j) {
        const size_t idx = idx0 + (size_t)j * 256;
        float s = 0.f;
#pragma unroll
        for (int z = 0; z < SPLITK; ++z) s += __bfloat162float(P[idx + z * stride]);
        s *= invRow[idx >> 10];          // row = idx / NCOL (NCOL = 1024)
        Y2[idx] = __float2bfloat16(2.0f * s - __bfloat162float(sub[idx]));
    }
}

// ---------------------------------------------------------------------------
// K4: per-node grouped GEMM via MFMA. out[b][n][o] = sum_k G[b][k] W[k][o] + bias
// B-frags read the pre-swizzled Wn: 16 B contiguous per lane, 1 KB per wave.
// One wave per node, 4 nodes per block. C/D layout: row=quad*4+r, col=l16.
// ---------------------------------------------------------------------------
__global__ __launch_bounds__(256) void final_kernel(
        const __hip_bfloat16* __restrict__ Xt, const __hip_bfloat16* __restrict__ Y1,
        const __hip_bfloat16* __restrict__ Y2, const __hip_bfloat16* __restrict__ Wn,
        const float* __restrict__ E, const float* __restrict__ bias_pool,
        float* __restrict__ out) {
    const int t    = threadIdx.x;
    const int lane = t & 63, wave = t >> 6;
    const int l16  = lane & 15, quad = lane >> 4;
    const int n    = blockIdx.x * 4 + wave;

    const __hip_bfloat16* srcs[3] = {Xt, Y1, Y2};
    const __hip_bfloat16* Wnode = Wn + (size_t)n * KIO;   // [c][ot][l16][kk]

    floatx4 acc[2][4] = {};   // [mt][ot]

#pragma unroll
    for (int c = 0; c < 3; ++c) {
        bf16x8 af[2];
#pragma unroll
        for (int mt = 0; mt < 2; ++mt)
            af[mt] = *(const bf16x8*)&srcs[c][(size_t)n * NCOL +
                                              (mt * 16 + l16) * 32 + quad * 8];
#pragma unroll
        for (int ot = 0; ot < 4; ++ot) {
            const bf16x8 bfr = *(const bf16x8*)&Wnode[(size_t)c * 2048 +
                                                      ot * 512 + l16 * 32 + quad * 8];
#pragma unroll
            for (int mt = 0; mt < 2; ++mt)
                acc[mt][ot] = __builtin_amdgcn_mfma_f32_16x16x32_bf16(
                                  af[mt], bfr, acc[mt][ot], 0, 0, 0);
        }
    }

    float en[DEMB];
#pragma unroll
    for (int d = 0; d < DEMB; ++d) en[d] = E[(size_t)n * DEMB + d];
#pragma unroll
    for (int ot = 0; ot < 4; ++ot) {
        float bv = 0.f;
        const int o = ot * 16 + l16;
#pragma unroll
        for (int d = 0; d < DEMB; ++d) bv += en[d] * bias_pool[d * COUT + o];
#pragma unroll
        for (int mt = 0; mt < 2; ++mt)
#pragma unroll
            for (int r = 0; r < 4; ++r) {
                const int b = mt * 16 + quad * 4 + r;
                out[((size_t)b * N_NODES + n) * COUT + o] = acc[mt][ot][r] + bv;
            }
    }
}

// ---------------------------------------------------------------------------
extern "C" void kernel_launch(void* const* d_in, const int* in_sizes, int n_in,
                              void* d_out, int out_size, void* d_ws, size_t ws_size,
                              hipStream_t stream) {
    (void)in_sizes; (void)n_in; (void)out_size; (void)ws_size;
    const float* x  = (const float*)d_in[0];
    const float* E  = (const float*)d_in[1];
    // d_in[2] = laplacian_mx, unused by the reference forward
    const float* Wp = (const float*)d_in[3];
    const float* bp = (const float*)d_in[4];
    float* out = (float*)d_out;

    char* ws = (char*)d_ws;
    __hip_bfloat16* U   = (__hip_bfloat16*)(ws);                 // 33554432 B (unnormalized exp)
    __hip_bfloat16* Xt  = (__hip_bfloat16*)(ws + 33554432);      //  8388608 B
    __hip_bfloat16* Bt1 = (__hip_bfloat16*)(ws + 41943040);      //  8388608 B (X^T; reused as Y2)
    __hip_bfloat16* Y1  = (__hip_bfloat16*)(ws + 50331648);      //  8388608 B
    __hip_bfloat16* Y1t = (__hip_bfloat16*)(ws + 58720256);      //  8388608 B
    __hip_bfloat16* P   = (__hip_bfloat16*)(ws + 67108864);      // 25165824 B bf16 partials [3][4096][1024]
    float*       invRow = (float*)(ws + 67108864 + 25165824);    //    16384 B (dead before Wn written)
    __hip_bfloat16* Wn  = (__hip_bfloat16*)(ws + 67108864);      // 50331648 B (SAME region: P+invRow dead before gen_w)
    // total ws use: 117440512 B

    compute_U_kernel<<<N_NODES / 8, 256, 0, stream>>>(E, U, invRow);
    transpose_kernel<<<dim3(N_NODES / 64, BATCH), 256, 0, stream>>>(x, Xt, Bt1);
    // Y1 = inv * (U @ X) : grid x = row-strip (XCD-co-locates A-strip sharers)
    gemm_splitk_kernel<<<dim3(N_NODES / 128, NCOL / 128, SPLITK), 256, 0, stream>>>(
        U, Bt1, P, N_NODES, NCOL, N_NODES);
    combine1_kernel<<<dim3(NCOL / 64, N_NODES / 64), 256, 0, stream>>>(
        P, invRow, Y1, Y1t, N_NODES, NCOL);
    // Y2 = 2*inv*(U @ Y1) - X
    gemm_splitk_kernel<<<dim3(N_NODES / 128, NCOL / 128, SPLITK), 256, 0, stream>>>(
        U, Y1t, P, N_NODES, NCOL, N_NODES);
    combine2_kernel<<<dim3(N_NODES * NCOL / 4096), 256, 0, stream>>>(
        P, invRow, Xt, Bt1, N_NODES, NCOL);
    // gen_w AFTER combine2: Wn shares the P/invRow region
    gen_w_kernel<<<dim3(24, N_NODES / 64), 256, 0, stream>>>(E, Wp, Wn);
    final_kernel<<<N_NODES / 4, 256, 0, stream>>>(Xt, Y1, Bt1, Wn, E, bp, out);
}